// Round 19
// baseline (439.076 us; speedup 1.0000x reference)
//
#include <hip/hip_runtime.h>
#include <math.h>

typedef __attribute__((ext_vector_type(8))) short bfrag;
typedef __attribute__((ext_vector_type(4))) float ffrag;

__device__ __forceinline__ unsigned short f2b(float v) {
  return (unsigned short)((__float_as_uint(v) + 0x8000u) >> 16);
}
__device__ __forceinline__ float b2f(unsigned short u) {
  return __uint_as_float((unsigned int)u << 16);
}

// load 16 f32, apply BN affine (feature = element index), pack to 2x uint4 bf16
__device__ __forceinline__ void cvtbn16(const float* __restrict__ p,
                                        const float4* sc, const float4* sh,
                                        uint4& o0, uint4& o1) {
  float4 v0 = ((const float4*)p)[0], v1 = ((const float4*)p)[1];
  float4 v2 = ((const float4*)p)[2], v3 = ((const float4*)p)[3];
  unsigned int a0 = (unsigned int)f2b(fmaf(v0.x,sc[0].x,sh[0].x)) |
                    ((unsigned int)f2b(fmaf(v0.y,sc[0].y,sh[0].y)) << 16);
  unsigned int a1 = (unsigned int)f2b(fmaf(v0.z,sc[0].z,sh[0].z)) |
                    ((unsigned int)f2b(fmaf(v0.w,sc[0].w,sh[0].w)) << 16);
  unsigned int a2 = (unsigned int)f2b(fmaf(v1.x,sc[1].x,sh[1].x)) |
                    ((unsigned int)f2b(fmaf(v1.y,sc[1].y,sh[1].y)) << 16);
  unsigned int a3 = (unsigned int)f2b(fmaf(v1.z,sc[1].z,sh[1].z)) |
                    ((unsigned int)f2b(fmaf(v1.w,sc[1].w,sh[1].w)) << 16);
  unsigned int a4 = (unsigned int)f2b(fmaf(v2.x,sc[2].x,sh[2].x)) |
                    ((unsigned int)f2b(fmaf(v2.y,sc[2].y,sh[2].y)) << 16);
  unsigned int a5 = (unsigned int)f2b(fmaf(v2.z,sc[2].z,sh[2].z)) |
                    ((unsigned int)f2b(fmaf(v2.w,sc[2].w,sh[2].w)) << 16);
  unsigned int a6 = (unsigned int)f2b(fmaf(v3.x,sc[3].x,sh[3].x)) |
                    ((unsigned int)f2b(fmaf(v3.y,sc[3].y,sh[3].y)) << 16);
  unsigned int a7 = (unsigned int)f2b(fmaf(v3.z,sc[3].z,sh[3].z)) |
                    ((unsigned int)f2b(fmaf(v3.w,sc[3].w,sh[3].w)) << 16);
  o0 = make_uint4(a0,a1,a2,a3);
  o1 = make_uint4(a4,a5,a6,a7);
}

// ===================== batched weight transpose -> bf16 [128][136] =====================
__global__ __launch_bounds__(256)
void k_w2bt6(const float* __restrict__ w0, const float* __restrict__ w1,
             const float* __restrict__ w2, const float* __restrict__ w3,
             const float* __restrict__ w4, const float* __restrict__ w5,
             unsigned short* __restrict__ out) {
  int t = blockIdx.x*256 + threadIdx.x;
  if (t >= 128*136) return;
  int L = blockIdx.y;
  const float* W; int Ksrc = 128;
  switch (L) {
    case 0: W = w0; Ksrc = 77; break;
    case 1: W = w1; break;
    case 2: W = w2; break;
    case 3: W = w3; break;
    case 4: W = w4; break;
    default: W = w5; break;
  }
  int n = t / 136, k = t - n*136;
  float v = (k < Ksrc) ? W[(size_t)k*128 + n] : 0.f;
  out[(size_t)L*128*136 + t] = f2b(v);
}

// ===================== per-batch GIN aggregation -> bf16 (in-LDS CSR) =====================
template<int KIN, int BNIN>
__global__ __launch_bounds__(256)
void k_gin_agg_b(const float* __restrict__ xg, const float* __restrict__ st,
                 const int* __restrict__ esrc, const int* __restrict__ edst,
                 unsigned short* __restrict__ xin) {
  __shared__ float xb[40*128];
  __shared__ unsigned short scsr[160];
  __shared__ int srow[41];
  const int b = blockIdx.x, tid = threadIdx.x, nbase = b*40;
  if (tid <= 40) srow[tid] = 0;
  __syncthreads();
  int rs = -1, rd = -1;
  if (tid < 160) {
    rs = esrc[b*160+tid] - nbase;
    rd = edst[b*160+tid] - nbase;
    atomicAdd(&srow[rd+1], 1);
  }
  for (int i = tid; i < 40*KIN; i += 256) {
    int n = i/KIN, f = i - n*KIN;
    float v = xg[(size_t)(nbase+n)*KIN + f];
    if (BNIN) v = fmaf(v, st[f], st[KIN+f]);
    xb[n*128 + f] = v;
  }
  __syncthreads();
  if (tid == 0) { int run = 0; for (int i = 1; i <= 40; ++i) { run += srow[i]; srow[i] = run; } }
  __syncthreads();
  if (tid < 160) { int slot = atomicAdd(&srow[rd], 1); scsr[slot] = (unsigned short)rs; }
  __syncthreads();
  for (int i = tid; i < 40*128; i += 256) {
    int n = i >> 7, f = i & 127;
    float a = 0.f;
    if (f < KIN) {
      a = xb[n*128 + f];
      int j0 = n ? srow[n-1] : 0, j1 = srow[n];
      for (int j = j0; j < j1; ++j) a += xb[scsr[j]*128 + f];
    }
    xin[(size_t)nbase*128 + i] = f2b(a);
  }
}

// ===================== fused GIN layer via MFMA =====================
__global__ __launch_bounds__(512)
void k_gin_fmfma(const unsigned short* __restrict__ Ax,
                 const unsigned short* __restrict__ W1t,
                 const unsigned short* __restrict__ W2t,
                 const float* __restrict__ b1, const float* __restrict__ b2,
                 float* __restrict__ outp, float* __restrict__ bnp) {
  __shared__ unsigned short Ab[128*136];
  __shared__ unsigned short W1l[128*136];
  __shared__ unsigned short W2l[128*136];
  __shared__ float cred[8*128], cred2[8*128];
  const int tid = threadIdx.x;
  const int row0 = blockIdx.x << 7;
  for (int i = tid; i < 128*17; i += 512) {
    int r = i / 17, c8 = (i - r*17) << 3;
    uint4 v = make_uint4(0,0,0,0);
    if (c8 < 128) v = *(const uint4*)(Ax + (size_t)(row0 + r)*128 + c8);
    *(uint4*)&Ab[r*136 + c8]  = v;
    *(uint4*)&W1l[r*136 + c8] = *(const uint4*)(W1t + r*136 + c8);
    *(uint4*)&W2l[r*136 + c8] = *(const uint4*)(W2t + r*136 + c8);
  }
  __syncthreads();
  const int wave = tid >> 6, lane = tid & 63;
  const int fr = lane & 15, fk = (lane >> 4) << 3;
  const int wrow = wave << 4;
  const int mrow = (lane >> 4) << 2;
  float b1v[8], b2v[8];
#pragma unroll
  for (int n = 0; n < 8; ++n) { b1v[n] = b1[(n<<4) + fr]; b2v[n] = b2[(n<<4) + fr]; }

  ffrag acc[8];
#pragma unroll
  for (int n = 0; n < 8; ++n) acc[n] = (ffrag){0.f,0.f,0.f,0.f};
#pragma unroll
  for (int s = 0; s < 4; ++s) {
    bfrag af = *(const bfrag*)&Ab[(wrow + fr)*136 + (s<<5) + fk];
#pragma unroll
    for (int n = 0; n < 8; ++n) {
      bfrag bf = *(const bfrag*)&W1l[((n<<4) + fr)*136 + (s<<5) + fk];
      acc[n] = __builtin_amdgcn_mfma_f32_16x16x32_bf16(af, bf, acc[n], 0, 0, 0);
    }
  }
#pragma unroll
  for (int n = 0; n < 8; ++n)
#pragma unroll
    for (int r = 0; r < 4; ++r) {
      float v = fmaxf(acc[n][r] + b1v[n], 0.f);
      Ab[(wrow + mrow + r)*136 + (n<<4) + fr] = f2b(v);
    }
  __syncthreads();

  ffrag acc2[8];
#pragma unroll
  for (int n = 0; n < 8; ++n) acc2[n] = (ffrag){0.f,0.f,0.f,0.f};
#pragma unroll
  for (int s = 0; s < 4; ++s) {
    bfrag af = *(const bfrag*)&Ab[(wrow + fr)*136 + (s<<5) + fk];
#pragma unroll
    for (int n = 0; n < 8; ++n) {
      bfrag bf = *(const bfrag*)&W2l[((n<<4) + fr)*136 + (s<<5) + fk];
      acc2[n] = __builtin_amdgcn_mfma_f32_16x16x32_bf16(af, bf, acc2[n], 0, 0, 0);
    }
  }
#pragma unroll
  for (int n = 0; n < 8; ++n) {
    float s = 0.f, q = 0.f;
#pragma unroll
    for (int r = 0; r < 4; ++r) {
      float v = fmaxf(acc2[n][r] + b2v[n], 0.f);
      outp[(size_t)(row0 + wrow + mrow + r)*128 + (n<<4) + fr] = v;
      s += v; q = fmaf(v, v, q);
    }
    s += __shfl_xor(s, 16); s += __shfl_xor(s, 32);
    q += __shfl_xor(q, 16); q += __shfl_xor(q, 32);
    if (lane < 16) { cred[wave*128 + (n<<4) + fr] = s; cred2[wave*128 + (n<<4) + fr] = q; }
  }
  __syncthreads();
  if (tid < 128) {
    float S = 0.f, Q = 0.f;
#pragma unroll
    for (int w = 0; w < 8; ++w) { S += cred[w*128 + tid]; Q += cred2[w*128 + tid]; }
    bnp[blockIdx.x*256 + tid] = S;
    bnp[blockIdx.x*256 + 128 + tid] = Q;
  }
}

// xd[b, L*128+f] = max_n affineBN(pre_L[b*40+n, f])
__global__ __launch_bounds__(128)
void k_drug_pool_bn(const float* __restrict__ p0, const float* __restrict__ p1,
                    const float* __restrict__ p2,
                    const float* __restrict__ s0, const float* __restrict__ s1,
                    const float* __restrict__ s2,
                    float* __restrict__ xd) {
  int b = blockIdx.x, f = threadIdx.x;
  const float* ps[3] = {p0,p1,p2};
  const float* ss[3] = {s0,s1,s2};
#pragma unroll
  for (int L = 0; L < 3; ++L) {
    float sc = ss[L][f], sh = ss[L][128+f];
    float m = -3.0e38f;
    const float* p = ps[L] + (size_t)b*40*128 + f;
    for (int n = 0; n < 40; ++n) m = fmaxf(m, fmaf(p[n*128], sc, sh));
    xd[(size_t)b*384 + L*128 + f] = m;
  }
}

// ===================== GEMM (f32, 64x64 tile) =====================
template<int ACT, int PART, int BNA, int NPA, int ACTA, int BNP>
__global__ __launch_bounds__(256)
void k_gemm(const float* __restrict__ A, int lda,
            const float* __restrict__ B, int ldb,
            const float* __restrict__ bias,
            float* __restrict__ C, int ldc, int Kchunk,
            long pstrideC, long pstrideA,
            const float* __restrict__ abias,
            const float* __restrict__ bnst,
            float* __restrict__ bnp) {
  __shared__ __align__(16) float As[32][68];
  __shared__ __align__(16) float Bs[32][68];
  const int tid = threadIdx.x;
  const int tx = tid & 15, ty = tid >> 4;
  const int row0 = blockIdx.y << 6, col0 = blockIdx.x << 6;
  const int kb = blockIdx.z * Kchunk;
  if (PART) C += (size_t)blockIdx.z * pstrideC;
  float acc[4][4] = {{0.f}};
  for (int k0 = 0; k0 < Kchunk; k0 += 32) {
#pragma unroll
    for (int i = 0; i < 2; ++i) {
      int idx = tid + (i << 8);
      int r = idx >> 3, c = (idx & 7) << 2;
      const float* ap = A + (size_t)(row0 + r)*lda + (kb + k0 + c);
      float4 v = *(const float4*)ap;
      if (NPA > 1) {
#pragma unroll
        for (int z = 1; z < NPA; ++z) {
          float4 p = *(const float4*)(ap + (size_t)z*pstrideA);
          v.x += p.x; v.y += p.y; v.z += p.z; v.w += p.w;
        }
        const float* ab = abias + (kb + k0 + c);
        v.x += ab[0]; v.y += ab[1]; v.z += ab[2]; v.w += ab[3];
        if (ACTA == 1) {
          v.x=fmaxf(v.x,0.f); v.y=fmaxf(v.y,0.f); v.z=fmaxf(v.z,0.f); v.w=fmaxf(v.w,0.f);
        } else if (ACTA == 2) {
          v.x = v.x>0.f?v.x:expm1f(v.x); v.y = v.y>0.f?v.y:expm1f(v.y);
          v.z = v.z>0.f?v.z:expm1f(v.z); v.w = v.w>0.f?v.w:expm1f(v.w);
        }
      }
      if (BNA) {
        int fb = (kb + k0 + c) & 15;
        float4 sc = *(const float4*)&bnst[fb];
        float4 sh = *(const float4*)&bnst[16 + fb];
        v.x = fmaf(v.x, sc.x, sh.x); v.y = fmaf(v.y, sc.y, sh.y);
        v.z = fmaf(v.z, sc.z, sh.z); v.w = fmaf(v.w, sc.w, sh.w);
      }
      int sw = ((c >> 2) & 7) << 2;
      int rs = r ^ sw;
      As[c+0][rs]=v.x; As[c+1][rs]=v.y; As[c+2][rs]=v.z; As[c+3][rs]=v.w;
    }
#pragma unroll
    for (int i = 0; i < 2; ++i) {
      int idx = tid + (i << 8);
      int r = idx >> 4, c = (idx & 15) << 2;
      *(float4*)&Bs[r][c] = *(const float4*)(B + (size_t)(kb + k0 + r)*ldb + (col0 + c));
    }
    __syncthreads();
#pragma unroll
    for (int kk = 0; kk < 32; ++kk) {
      int sw = ((kk >> 2) & 7) << 2;
      float4 av = *(const float4*)&As[kk][(ty << 2) ^ sw];
      float4 bv = *(const float4*)&Bs[kk][tx << 2];
      acc[0][0]=fmaf(av.x,bv.x,acc[0][0]); acc[0][1]=fmaf(av.x,bv.y,acc[0][1]);
      acc[0][2]=fmaf(av.x,bv.z,acc[0][2]); acc[0][3]=fmaf(av.x,bv.w,acc[0][3]);
      acc[1][0]=fmaf(av.y,bv.x,acc[1][0]); acc[1][1]=fmaf(av.y,bv.y,acc[1][1]);
      acc[1][2]=fmaf(av.y,bv.z,acc[1][2]); acc[1][3]=fmaf(av.y,bv.w,acc[1][3]);
      acc[2][0]=fmaf(av.z,bv.x,acc[2][0]); acc[2][1]=fmaf(av.z,bv.y,acc[2][1]);
      acc[2][2]=fmaf(av.z,bv.z,acc[2][2]); acc[2][3]=fmaf(av.z,bv.w,acc[2][3]);
      acc[3][0]=fmaf(av.w,bv.x,acc[3][0]); acc[3][1]=fmaf(av.w,bv.y,acc[3][1]);
      acc[3][2]=fmaf(av.w,bv.z,acc[3][2]); acc[3][3]=fmaf(av.w,bv.w,acc[3][3]);
    }
    __syncthreads();
  }
#pragma unroll
  for (int i = 0; i < 4; ++i) {
    int r = row0 + (ty<<2) + i, c = col0 + (tx<<2);
    float4 v = make_float4(acc[i][0], acc[i][1], acc[i][2], acc[i][3]);
    if (!PART) {
      if (bias) { v.x += bias[c]; v.y += bias[c+1]; v.z += bias[c+2]; v.w += bias[c+3]; }
      if (ACT == 1) { v.x=fmaxf(v.x,0.f); v.y=fmaxf(v.y,0.f); v.z=fmaxf(v.z,0.f); v.w=fmaxf(v.w,0.f); }
      else if (ACT == 2) {
        v.x = v.x>0.f?v.x:expm1f(v.x); v.y = v.y>0.f?v.y:expm1f(v.y);
        v.z = v.z>0.f?v.z:expm1f(v.z); v.w = v.w>0.f?v.w:expm1f(v.w);
      }
    }
    *(float4*)(C + (size_t)r*ldc + c) = v;
  }
}

template<int ACT>
__global__ void k_reduce(const float* __restrict__ parts, int np, long pstride,
                         const float* __restrict__ bias,
                         float* __restrict__ out, int ldo, int M, int N) {
  int t = blockIdx.x*blockDim.x + threadIdx.x;
  if (t >= M*N) return;
  int r = t / N, c = t - r*N;
  float s = 0.f;
  for (int z = 0; z < np; ++z) s += parts[(size_t)z*pstride + t];
  s += bias[c];
  if (ACT == 1) s = fmaxf(s, 0.f);
  else if (ACT == 2) s = s > 0.f ? s : expm1f(s);
  out[(size_t)r*ldo + c] = s;
}

// ===================== bf16 weight transpose (cemb1 B) =====================
__global__ __launch_bounds__(256)
void k_w2bt(const float* __restrict__ W, unsigned short* __restrict__ Bt) {
  __shared__ float tile[32][33];
  int bk = blockIdx.x << 5, bn = blockIdx.y << 5;
  int c = threadIdx.x & 31, r8 = threadIdx.x >> 5;
#pragma unroll
  for (int i = 0; i < 4; ++i) {
    int r = r8 + (i << 3);
    tile[r][c] = W[(size_t)(bk + r)*1024 + bn + c];
  }
  __syncthreads();
#pragma unroll
  for (int i = 0; i < 4; ++i) {
    int r = r8 + (i << 3);
    Bt[(size_t)(bn + r)*6400 + bk + c] = f2b(tile[c][r]);
  }
}

// ===================== MFMA bf16 GEMM: f32 A + BN inline, 128x128, split-K =====
__global__ __launch_bounds__(256)
void k_mfma128(const float* __restrict__ A,
               const unsigned short* __restrict__ Bt,
               const float* __restrict__ bnst,
               float* __restrict__ C, int ldc, int K,
               int Kchunk, long pstrideC) {
  __shared__ unsigned short Al[2][128*40];
  __shared__ unsigned short Bl[2][128*40];
  const int tid = threadIdx.x;
  const int row0 = blockIdx.y << 7, col0 = blockIdx.x << 7;
  const int kb = blockIdx.z * Kchunk;
  C += (size_t)blockIdx.z * pstrideC;
  const int wave = tid >> 6, lane = tid & 63;
  const int wr = wave >> 1, wc = wave & 1;
  const int fr = lane & 15, fk = (lane >> 4) << 3;
  const int lr = tid >> 1, lco = (tid & 1) << 4;

  float4 sc[4], sh[4];
#pragma unroll
  for (int i = 0; i < 4; ++i) {
    sc[i] = *(const float4*)&bnst[i*4];
    sh[i] = *(const float4*)&bnst[16 + i*4];
  }

  ffrag acc[4][4];
#pragma unroll
  for (int i = 0; i < 4; ++i)
#pragma unroll
    for (int n = 0; n < 4; ++n) acc[i][n] = (ffrag){0.f, 0.f, 0.f, 0.f};

  const float* ag = A + (size_t)(row0 + lr)*K + kb + lco;
  const unsigned short* bg = Bt + (size_t)(col0 + lr)*K + kb + lco;

  uint4 ra0, ra1;
  cvtbn16(ag, sc, sh, ra0, ra1);
  uint4 rb0 = *(const uint4*)bg, rb1 = *(const uint4*)(bg + 8);
  *(uint4*)&Al[0][lr*40 + lco] = ra0; *(uint4*)&Al[0][lr*40 + lco + 8] = ra1;
  *(uint4*)&Bl[0][lr*40 + lco] = rb0; *(uint4*)&Bl[0][lr*40 + lco + 8] = rb1;
  __syncthreads();

  const int NS = Kchunk >> 5;
  int cur = 0;
  for (int s = 0; s < NS; ++s) {
    if (s + 1 < NS) {
      cvtbn16(ag + ((s + 1) << 5), sc, sh, ra0, ra1);
      const unsigned short* bn = bg + ((s + 1) << 5);
      rb0 = *(const uint4*)bn; rb1 = *(const uint4*)(bn + 8);
    }
    bfrag af[4], bf[4];
#pragma unroll
    for (int i = 0; i < 4; ++i) af[i] = *(const bfrag*)&Al[cur][(wr*64 + i*16 + fr)*40 + fk];
#pragma unroll
    for (int n = 0; n < 4; ++n) bf[n] = *(const bfrag*)&Bl[cur][(wc*64 + n*16 + fr)*40 + fk];
#pragma unroll
    for (int i = 0; i < 4; ++i)
#pragma unroll
      for (int n = 0; n < 4; ++n)
        acc[i][n] = __builtin_amdgcn_mfma_f32_16x16x32_bf16(af[i], bf[n], acc[i][n], 0, 0, 0);
    if (s + 1 < NS) {
      cur ^= 1;
      *(uint4*)&Al[cur][lr*40 + lco] = ra0; *(uint4*)&Al[cur][lr*40 + lco + 8] = ra1;
      *(uint4*)&Bl[cur][lr*40 + lco] = rb0; *(uint4*)&Bl[cur][lr*40 + lco + 8] = rb1;
      __syncthreads();
    }
  }
  const int frow = (lane >> 4) << 2;
#pragma unroll
  for (int i = 0; i < 4; ++i)
#pragma unroll
    for (int n = 0; n < 4; ++n) {
      float* cp = C + (size_t)(row0 + wr*64 + i*16 + frow)*ldc + col0 + wc*64 + n*16 + fr;
#pragma unroll
      for (int r = 0; r < 4; ++r) cp[(size_t)r*ldc] = acc[i][n][r];
    }
}

// ===================== BN finalize: partials -> affine (scale, shift) =====================
__global__ void k_bn_fin(const float* __restrict__ parts, int nb, int C, float invn,
                         const float* __restrict__ g, const float* __restrict__ be,
                         float* __restrict__ stats) {
  int f = threadIdx.x;
  if (f >= C) return;
  float s = 0.f, s2 = 0.f;
#pragma unroll 4
  for (int z = 0; z < nb; ++z) { s += parts[z*2*C + f]; s2 += parts[z*2*C + C + f]; }
  float mu = s*invn;
  float var = fmaxf(s2*invn - mu*mu, 0.f);
  float rstd = rsqrtf(var + 1e-5f);
  float sc = g ? g[f]*rstd : rstd;
  stats[f] = sc;
  stats[C+f] = (be ? be[f] : 0.f) - mu*sc;
}

// ===================== fused per-batch GAT layer =====================
// Degree-sorted gather order (3-phase counting sort, with the barrier between
// the CSR scatter and the histogram that round 18 was missing).
template<int NODES, int NPOOL, int KIN, int MAXE, int SORTED, int BNIN, int NT>
__global__ __launch_bounds__(NT, 8)
void k_gat_lds(const float* __restrict__ x,
               const int* __restrict__ esrc, const int* __restrict__ edst, int Earg,
               const float* __restrict__ W, const float* __restrict__ as_,
               const float* __restrict__ ad_, const float* __restrict__ bias,
               const int* __restrict__ cluster,
               const float* __restrict__ instats,
               float* __restrict__ pooled, float* __restrict__ bnp) {
  constexpr int EIT = (MAXE + NT - 1) / NT;
  __shared__ unsigned int shp[NODES*9];   // h as packed bf16 pairs, stride 9
  __shared__ unsigned int spk[MAXE];
  __shared__ float sss[NODES], ssd[NODES];
  __shared__ int srow[NODES+1];
  __shared__ unsigned short sorder[NODES];
  __shared__ int shist[64];
  __shared__ int scur[64];
  __shared__ float sWl[KIN*16 + 16];
  __shared__ float sas[16], sad[16];
  __shared__ int schunk[32];
  __shared__ int sr2[2];
  const int b = blockIdx.x;
  const int tid = threadIdx.x;
  const int nbase = b*NODES;

  if (tid < KIN*16) sWl[tid] = W[tid];
  if (tid >= 64 && tid < 80)  sWl[KIN*16 + tid-64] = bias[tid-64];
  if (tid >= 80 && tid < 96)  sas[tid-80] = as_[tid-80];
  if (tid >= 96 && tid < 112) sad[tid-96] = ad_[tid-96];
  if (tid >= 128 && tid < 192) shist[tid-128] = 0;
  if (SORTED && tid == 0) {
    int a = 0, c = Earg;
    while (a < c) { int m = (a+c) >> 1; if (esrc[m] < nbase) a = m+1; else c = m; }
    sr2[0] = a;
    c = Earg;
    int nend = nbase + NODES;
    while (a < c) { int m = (a+c) >> 1; if (esrc[m] < nend) a = m+1; else c = m; }
    sr2[1] = a;
  }
  for (int i = tid; i <= NODES; i += NT) srow[i] = 0;
  __syncthreads();

  int e0, Eblk;
  if (SORTED) { e0 = sr2[0]; Eblk = sr2[1] - sr2[0]; }
  else        { e0 = b*Earg; Eblk = Earg; }

  int ers[EIT], erd[EIT];
#pragma unroll
  for (int it = 0; it < EIT; ++it) {
    int e = tid + it*NT;
    ers[it] = -1; erd[it] = -1;
    if (e < Eblk) {
      ers[it] = esrc[e0+e] - nbase;
      erd[it] = edst[e0+e] - nbase;
      atomicAdd(&srow[erd[it]+1], 1);
    }
  }
  // h = x@W; pack adjacent-feature pairs via shfl (f parity == lane parity)
  for (int i = tid; i < NODES*16; i += NT) {
    int n = i >> 4, f = i & 15;
    const float* xp = x + (size_t)(nbase + n)*KIN;
    float xq = (f < KIN) ? xp[f] : 0.f;
    if (BNIN && f < KIN) xq = fmaf(xq, instats[f], instats[16+f]);
    float hv = 0.f;
#pragma unroll
    for (int j = 0; j < KIN; ++j) hv = fmaf(__shfl(xq, j, 16), sWl[j*16 + f], hv);
    unsigned int hb = (unsigned int)f2b(hv);
    unsigned int partner = (unsigned int)__shfl_xor((int)hb, 1);
    if ((f & 1) == 0) shp[n*9 + (f >> 1)] = hb | (partner << 16);
    float s1 = hv * sas[f], s2 = hv * sad[f];
#pragma unroll
    for (int m = 8; m >= 1; m >>= 1) { s1 += __shfl_xor(s1, m); s2 += __shfl_xor(s2, m); }
    if (f == 0) { sss[n] = s1; ssd[n] = s2; }
  }
  __syncthreads();

  constexpr int NC = 32, CS = (NODES + NC - 1) / NC;
  if (tid < NC) {
    int run = 0, lo = tid*CS, hi = (tid+1)*CS < NODES ? (tid+1)*CS : NODES;
    for (int i = lo; i < hi; ++i) { run += srow[i+1]; srow[i+1] = run; }
    schunk[tid] = run;
  }
  __syncthreads();
  if (tid == 0) { int base = 0; for (int c = 0; c < NC; ++c) { int t2 = schunk[c]; schunk[c] = base; base += t2; } }
  __syncthreads();
  for (int i = tid; i < NODES; i += NT) srow[i+1] += schunk[i/CS];
  __syncthreads();

#pragma unroll
  for (int it = 0; it < EIT; ++it) {
    if (erd[it] >= 0) {
      int slot = atomicAdd(&srow[erd[it]], 1);
      float l = sss[ers[it]] + ssd[erd[it]];
      l = fmaxf(l, 0.2f*l);
      float ex = __expf(l);
      spk[slot] = ((__float_as_uint(ex) + 0x8000u) & 0xffff0000u) | (unsigned int)ers[it];
    }
  }
  __syncthreads();   // srow final (end offsets) before degree reads — was missing in r18

  // ---- counting sort of nodes by degree (3 clean phases) ----
  for (int n = tid; n < NODES; n += NT) {
    int deg = srow[n] - (n ? srow[n-1] : 0);
    atomicAdd(&shist[min(deg, 63)], 1);
  }
  __syncthreads();
  if (tid == 0) {
    int run = 0;
    for (int d = 0; d < 64; ++d) { scur[d] = run; run += shist[d]; }
  }
  __syncthreads();
  for (int n = tid; n < NODES; n += NT) {
    int deg = srow[n] - (n ? srow[n-1] : 0);
    int pos = atomicAdd(&scur[min(deg, 63)], 1);
    sorder[pos] = (unsigned short)n;
  }
  __syncthreads();

  {
    const int lane = tid & 7, grp = tid >> 3;   // NT/8 node groups
    for (int ni = grp; ni < NODES; ni += (NT >> 3)) {
      int n = sorder[ni];
      float ls = sss[n] + ssd[n];
      ls = fmaxf(ls, 0.2f*ls);
      float exs = __expf(ls);
      unsigned int hp = shp[n*9 + lane];
      float aLo = exs * b2f((unsigned short)hp);
      float aHi = exs * b2f((unsigned short)(hp >> 16));
      float sum = exs;
      int j = (n > 0) ? srow[n-1] : 0, j1 = srow[n];
      for (; j + 4 <= j1; j += 4) {
        unsigned int p0 = spk[j], p1 = spk[j+1], p2 = spk[j+2], p3 = spk[j+3];
        float e0 = __uint_as_float(p0 & 0xffff0000u);
        float e1 = __uint_as_float(p1 & 0xffff0000u);
        float e2 = __uint_as_float(p2 & 0xffff0000u);
        float e3 = __uint_as_float(p3 & 0xffff0000u);
        unsigned int h0 = shp[(p0 & 0xffffu)*9 + lane];
        unsigned int h1 = shp[(p1 & 0xffffu)*9 + lane];
        unsigned int h2 = shp[(p2 & 0xffffu)*9 + lane];
        unsigned int h3 = shp[(p3 & 0xffffu)*9 + lane];
        aLo = fmaf(e0, b2f((unsigned short)h0), aLo);
        aHi = fmaf(e0, b2f((unsigned short)(h0 >> 16)), aHi); sum += e0;
        aLo = fmaf(e1, b2f((unsigned short)h1), aLo);
        aHi = fmaf(e1, b2f((unsigned short)(h1 >> 16)), aHi); sum += e1;
        aLo = fmaf(e2, b2f((unsigned short)h2), aLo);
        aHi = fmaf(e2, b2f((unsigned short)(h2 >> 16)), aHi); sum += e2;
        aLo = fmaf(e3, b2f((unsigned short)h3), aLo);
        aHi = fmaf(e3, b2f((unsigned short)(h3 >> 16)), aHi); sum += e3;
      }
      for (; j < j1; ++j) {
        unsigned int p0 = spk[j];
        float e0 = __uint_as_float(p0 & 0xffff0000u);
        unsigned int h0 = shp[(p0 & 0xffffu)*9 + lane];
        aLo = fmaf(e0, b2f((unsigned short)h0), aLo);
        aHi = fmaf(e0, b2f((unsigned short)(h0 >> 16)), aHi); sum += e0;
      }
      float inv = 1.f / sum;
      float vLo = fmaxf(fmaf(aLo, inv, sWl[KIN*16 + 2*lane]), 0.f);
      float vHi = fmaxf(fmaf(aHi, inv, sWl[KIN*16 + 2*lane + 1]), 0.f);
      int* pp = (int*)pooled + (size_t)cluster[nbase + n]*16 + 2*lane;
      atomicMax(pp,     __float_as_int(vLo));
      atomicMax(pp + 1, __float_as_int(vHi));
    }
  }
  __syncthreads();   // drains this block's atomics (vmcnt(0) before barrier)

  // BN partials over this block's exclusive pooled slice
  {
    float s = 0.f, q = 0.f;
    const float* po = pooled + (size_t)b*NPOOL*16;
    int f = tid & 15;
    for (int r = tid >> 4; r < NPOOL; r += (NT >> 4)) {
      float v = po[r*16 + f];
      s += v; q = fmaf(v, v, q);
    }
    float* red = (float*)shp;          // >= 2*NT floats
    red[tid] = s; red[NT + tid] = q;
    __syncthreads();
    for (int o = NT >> 1; o >= 16; o >>= 1) {
      if (tid < o) { red[tid] += red[tid + o]; red[NT + tid] += red[NT + tid + o]; }
      __syncthreads();
    }
    if (tid < 16) { bnp[b*32 + tid] = red[tid]; bnp[b*32 + 16 + tid] = red[NT + tid]; }
  }
}

// ===================== final GEMV =====================
__global__ __launch_bounds__(64)
void k_gemv_out(const float* __restrict__ parts, long pstrideA,
                const float* __restrict__ abias,
                const float* __restrict__ w,
                const float* __restrict__ b, float* __restrict__ out) {
  int r = blockIdx.x, l = threadIdx.x;
  float s = 0.f;
  for (int k = l; k < 384; k += 64) {
    const float* p = parts + (size_t)r*384 + k;
    float h = p[0] + p[pstrideA] + p[2*pstrideA] + p[3*pstrideA] + abias[k];
    h = h > 0.f ? h : expm1f(h);
    s = fmaf(h, w[k], s);
  }
#pragma unroll
  for (int o = 32; o > 0; o >>= 1) s += __shfl_down(s, o);
  if (l == 0) out[r] = s + b[0];
}

// ===================== host orchestration =====================
extern "C" void kernel_launch(void* const* d_in, const int* in_sizes, int n_in,
                              void* d_out, int out_size, void* d_ws, size_t ws_size,
                              hipStream_t stream) {
  (void)n_in; (void)out_size;
  const int B = 512;
  const int nd  = B*40;
  const int nc1 = B*512;
  const int nc2 = B*400;
  const int Ec0 = in_sizes[42]/2;
  const int Ec1 = in_sizes[43]/2;

  const float* drug_x = (const float*)d_in[0];
  const float* cell_x = (const float*)d_in[1];
  const float* gW1[3] = {(const float*)d_in[2],(const float*)d_in[8],(const float*)d_in[14]};
  const float* gb1[3] = {(const float*)d_in[3],(const float*)d_in[9],(const float*)d_in[15]};
  const float* gW2[3] = {(const float*)d_in[4],(const float*)d_in[10],(const float*)d_in[16]};
  const float* gb2[3] = {(const float*)d_in[5],(const float*)d_in[11],(const float*)d_in[17]};
  const float* gg [3] = {(const float*)d_in[6],(const float*)d_in[12],(const float*)d_in[18]};
  const float* gbe[3] = {(const float*)d_in[7],(const float*)d_in[13],(const float*)d_in[19]};
  const float* demb_W = (const float*)d_in[20]; const float* demb_b = (const float*)d_in[21];
  const float* gatW[2]  = {(const float*)d_in[22],(const float*)d_in[26]};
  const float* gatAS[2] = {(const float*)d_in[23],(const float*)d_in[27]};
  const float* gatAD[2] = {(const float*)d_in[24],(const float*)d_in[28]};
  const float* gatB[2]  = {(const float*)d_in[25],(const float*)d_in[29]};
  const float* cembW1 = (const float*)d_in[30]; const float* cembb1 = (const float*)d_in[31];
  const float* cembW2 = (const float*)d_in[32]; const float* cembb2 = (const float*)d_in[33];
  const float* regW1 = (const float*)d_in[34]; const float* regb1 = (const float*)d_in[35];
  const float* regW2 = (const float*)d_in[36]; const float* regb2 = (const float*)d_in[37];
  const float* regW3 = (const float*)d_in[38]; const float* regb3 = (const float*)d_in[39];
  const int* dei = (const int*)d_in[40];
  const int* ei0 = (const int*)d_in[42];
  const int* ei1 = (const int*)d_in[43];
  const int* cl0 = (const int*)d_in[44];
  const int* cl1 = (const int*)d_in[45];
  const int Ed  = in_sizes[40]/2;
  const int *dsrc = dei, *ddst = dei + Ed;
  const int *src0 = ei0, *dst0 = ei0 + Ec0;
  const int *src1 = ei1, *dst1 = ei1 + Ec1;
  float* out = (float*)d_out;

  // ---- workspace layout ----
  char* base = (char*)d_ws; size_t off = 0;
  auto AL = [&](size_t bytes)->char* { char* p = base + off; off = (off + bytes + 255) & ~(size_t)255; return p; };
  float* h_cat   = (float*)AL((size_t)512*384*4);
  float* xd      = (float*)AL((size_t)512*384*4);
  float* pooled1 = (float*)AL((size_t)nc1*16*4);
  float* pooled2 = (float*)AL((size_t)nc2*16*4);
  float* st_g0   = (float*)AL(256*4);
  float* st_g1   = (float*)AL(256*4);
  float* st_g2   = (float*)AL(256*4);
  float* st16_0  = (float*)AL(32*4);
  float* st16_1  = (float*)AL(32*4);
  float* bparts  = (float*)AL((size_t)512*256*4);
  unsigned short* Wt6 = (unsigned short*)AL((size_t)6*128*136*2);
  char*  S       = base + off;
  if (ws_size < off + (size_t)53*1024*1024) return;

  dim3 b256(256);

  // drug-phase scratch (S)
  float* pre0 = (float*)(S);
  float* pre1 = pre0 + (size_t)nd*128;
  float* pre2 = pre1 + (size_t)nd*128;
  unsigned short* xin_b = (unsigned short*)(pre2 + (size_t)nd*128);
  float* pre[3] = {pre0, pre1, pre2};
  float* stg[3] = {st_g0, st_g1, st_g2};

  // cell-phase scratch (S, reused after drug pool)
  size_t so = 0;
  auto SB = [&](size_t bytes)->char* { char* p = S + so; so = (so + bytes + 255) & ~(size_t)255; return p; };
  unsigned short* Btb = (unsigned short*)SB((size_t)1024*6400*2);
  float* parts1 = (float*)SB((size_t)8*512*1024*4);
  float* parts2 = (float*)SB((size_t)8*512*256*4);
  float* partsA = (float*)SB((size_t)4*512*384*4);
  float* partsB = (float*)SB((size_t)4*512*384*4);
  float* cembh  = (float*)SB((size_t)512*1024*4);

  // ================= DRUG BRANCH (bf16 MFMA GIN) =================
  k_w2bt6<<<dim3(68, 6), b256, 0, stream>>>(gW1[0], gW1[1], gW1[2],
                                            gW2[0], gW2[1], gW2[2], Wt6);
  for (int L = 0; L < 3; ++L) {
    if (L == 0)
      k_gin_agg_b<77,0><<<dim3(512), b256, 0, stream>>>(drug_x, nullptr, dsrc, ddst, xin_b);
    else
      k_gin_agg_b<128,1><<<dim3(512), b256, 0, stream>>>(pre[L-1], stg[L-1], dsrc, ddst, xin_b);
    k_gin_fmfma<<<dim3(160), dim3(512), 0, stream>>>(
        xin_b, Wt6 + (size_t)L*128*136, Wt6 + (size_t)(3+L)*128*136,
        gb1[L], gb2[L], pre[L], bparts);
    k_bn_fin<<<dim3(1), dim3(128), 0, stream>>>(bparts, 160, 128, 1.f/nd, gg[L], gbe[L], stg[L]);
  }
  k_drug_pool_bn<<<dim3(512), dim3(128), 0, stream>>>(pre0, pre1, pre2, st_g0, st_g1, st_g2, xd);
  k_gemm<1,0,0,0,0,0><<<dim3(2,8,1), b256, 0, stream>>>(
      xd, 384, demb_W, 128, demb_b, h_cat, 384, 384, 0, 0, nullptr, nullptr, nullptr);

  // cembW1 -> bf16 transposed (drug scratch dead now)
  k_w2bt<<<dim3(200, 32), b256, 0, stream>>>(cembW1, Btb);

  // ================= CELL BRANCH: two fused GAT layers =================
  k_gat_lds<706,512,3,8000,0,0,1024><<<dim3(512), dim3(1024), 0, stream>>>(
      cell_x, src0, dst0, Ec0/512, gatW[0], gatAS[0], gatAD[0], gatB[0], cl0,
      nullptr, pooled1, bparts);
  k_bn_fin<<<dim3(1), dim3(16), 0, stream>>>(bparts, 512, 16, 1.f/nc1, nullptr, nullptr, st16_0);

  k_gat_lds<512,400,16,8000,1,1,1024><<<dim3(512), dim3(1024), 0, stream>>>(
      pooled1, src1, dst1, Ec1, gatW[1], gatAS[1], gatAD[1], gatB[1], cl1,
      st16_0, pooled2, bparts);
  k_bn_fin<<<dim3(1), dim3(16), 0, stream>>>(bparts, 512, 16, 1.f/nc2, nullptr, nullptr, st16_1);

  // ================= cell embedding MLP (BN+bf16 fused into MFMA A-staging) =====
  k_mfma128<<<dim3(8, 4, 8), b256, 0, stream>>>(
      pooled2, Btb, st16_1, parts1, 1024, 6400, 800, (long)512*1024);
  k_reduce<1><<<dim3((512*1024+255)/256), b256, 0, stream>>>(
      parts1, 8, (long)512*1024, cembb1, cembh, 1024, 512, 1024);
  k_gemm<0,1,0,0,0,0><<<dim3(4,8,8), b256, 0, stream>>>(
      cembh, 1024, cembW2, 256, nullptr, parts2, 256, 128,
      (long)512*256, 0, nullptr, nullptr, nullptr);
  k_reduce<1><<<dim3((512*256+255)/256), b256, 0, stream>>>(
      parts2, 8, (long)512*256, cembb2, h_cat + 128, 384, 512, 256);

  // ================= regressor =================
  k_gemm<0,1,0,0,0,0><<<dim3(6,8,4), b256, 0, stream>>>(
      h_cat, 384, regW1, 384, nullptr, partsA, 384, 96,
      (long)512*384, 0, nullptr, nullptr, nullptr);
  k_gemm<0,1,0,4,2,0><<<dim3(6,8,4), b256, 0, stream>>>(
      partsA, 384, regW2, 384, nullptr, partsB, 384, 96,
      (long)512*384, (long)512*384, regb1, nullptr, nullptr);
  k_gemv_out<<<dim3(512), dim3(64), 0, stream>>>(
      partsB, (long)512*384, regb2, regW3, regb3, out);
}

// Round 20
// 437.385 us; speedup vs baseline: 1.0039x; 1.0039x over previous
//
#include <hip/hip_runtime.h>
#include <math.h>

typedef __attribute__((ext_vector_type(8))) short bfrag;
typedef __attribute__((ext_vector_type(4))) float ffrag;

__device__ __forceinline__ unsigned short f2b(float v) {
  return (unsigned short)((__float_as_uint(v) + 0x8000u) >> 16);
}
__device__ __forceinline__ float b2f(unsigned short u) {
  return __uint_as_float((unsigned int)u << 16);
}

// load 16 f32, apply BN affine (feature = element index), pack to 2x uint4 bf16
__device__ __forceinline__ void cvtbn16(const float* __restrict__ p,
                                        const float4* sc, const float4* sh,
                                        uint4& o0, uint4& o1) {
  float4 v0 = ((const float4*)p)[0], v1 = ((const float4*)p)[1];
  float4 v2 = ((const float4*)p)[2], v3 = ((const float4*)p)[3];
  unsigned int a0 = (unsigned int)f2b(fmaf(v0.x,sc[0].x,sh[0].x)) |
                    ((unsigned int)f2b(fmaf(v0.y,sc[0].y,sh[0].y)) << 16);
  unsigned int a1 = (unsigned int)f2b(fmaf(v0.z,sc[0].z,sh[0].z)) |
                    ((unsigned int)f2b(fmaf(v0.w,sc[0].w,sh[0].w)) << 16);
  unsigned int a2 = (unsigned int)f2b(fmaf(v1.x,sc[1].x,sh[1].x)) |
                    ((unsigned int)f2b(fmaf(v1.y,sc[1].y,sh[1].y)) << 16);
  unsigned int a3 = (unsigned int)f2b(fmaf(v1.z,sc[1].z,sh[1].z)) |
                    ((unsigned int)f2b(fmaf(v1.w,sc[1].w,sh[1].w)) << 16);
  unsigned int a4 = (unsigned int)f2b(fmaf(v2.x,sc[2].x,sh[2].x)) |
                    ((unsigned int)f2b(fmaf(v2.y,sc[2].y,sh[2].y)) << 16);
  unsigned int a5 = (unsigned int)f2b(fmaf(v2.z,sc[2].z,sh[2].z)) |
                    ((unsigned int)f2b(fmaf(v2.w,sc[2].w,sh[2].w)) << 16);
  unsigned int a6 = (unsigned int)f2b(fmaf(v3.x,sc[3].x,sh[3].x)) |
                    ((unsigned int)f2b(fmaf(v3.y,sc[3].y,sh[3].y)) << 16);
  unsigned int a7 = (unsigned int)f2b(fmaf(v3.z,sc[3].z,sh[3].z)) |
                    ((unsigned int)f2b(fmaf(v3.w,sc[3].w,sh[3].w)) << 16);
  o0 = make_uint4(a0,a1,a2,a3);
  o1 = make_uint4(a4,a5,a6,a7);
}

// ===================== batched weight transpose -> bf16 [128][136] =====================
__global__ __launch_bounds__(256)
void k_w2bt6(const float* __restrict__ w0, const float* __restrict__ w1,
             const float* __restrict__ w2, const float* __restrict__ w3,
             const float* __restrict__ w4, const float* __restrict__ w5,
             unsigned short* __restrict__ out) {
  int t = blockIdx.x*256 + threadIdx.x;
  if (t >= 128*136) return;
  int L = blockIdx.y;
  const float* W; int Ksrc = 128;
  switch (L) {
    case 0: W = w0; Ksrc = 77; break;
    case 1: W = w1; break;
    case 2: W = w2; break;
    case 3: W = w3; break;
    case 4: W = w4; break;
    default: W = w5; break;
  }
  int n = t / 136, k = t - n*136;
  float v = (k < Ksrc) ? W[(size_t)k*128 + n] : 0.f;
  out[(size_t)L*128*136 + t] = f2b(v);
}

// ===================== per-batch GIN aggregation -> bf16 (in-LDS CSR) =====================
template<int KIN, int BNIN>
__global__ __launch_bounds__(256)
void k_gin_agg_b(const float* __restrict__ xg, const float* __restrict__ st,
                 const int* __restrict__ esrc, const int* __restrict__ edst,
                 unsigned short* __restrict__ xin) {
  __shared__ float xb[40*128];
  __shared__ unsigned short scsr[160];
  __shared__ int srow[41];
  const int b = blockIdx.x, tid = threadIdx.x, nbase = b*40;
  if (tid <= 40) srow[tid] = 0;
  __syncthreads();
  int rs = -1, rd = -1;
  if (tid < 160) {
    rs = esrc[b*160+tid] - nbase;
    rd = edst[b*160+tid] - nbase;
    atomicAdd(&srow[rd+1], 1);
  }
  for (int i = tid; i < 40*KIN; i += 256) {
    int n = i/KIN, f = i - n*KIN;
    float v = xg[(size_t)(nbase+n)*KIN + f];
    if (BNIN) v = fmaf(v, st[f], st[KIN+f]);
    xb[n*128 + f] = v;
  }
  __syncthreads();
  if (tid == 0) { int run = 0; for (int i = 1; i <= 40; ++i) { run += srow[i]; srow[i] = run; } }
  __syncthreads();
  if (tid < 160) { int slot = atomicAdd(&srow[rd], 1); scsr[slot] = (unsigned short)rs; }
  __syncthreads();
  for (int i = tid; i < 40*128; i += 256) {
    int n = i >> 7, f = i & 127;
    float a = 0.f;
    if (f < KIN) {
      a = xb[n*128 + f];
      int j0 = n ? srow[n-1] : 0, j1 = srow[n];
      for (int j = j0; j < j1; ++j) a += xb[scsr[j]*128 + f];
    }
    xin[(size_t)nbase*128 + i] = f2b(a);
  }
}

// ===================== fused GIN layer via MFMA =====================
__global__ __launch_bounds__(512)
void k_gin_fmfma(const unsigned short* __restrict__ Ax,
                 const unsigned short* __restrict__ W1t,
                 const unsigned short* __restrict__ W2t,
                 const float* __restrict__ b1, const float* __restrict__ b2,
                 float* __restrict__ outp, float* __restrict__ bnp) {
  __shared__ unsigned short Ab[128*136];
  __shared__ unsigned short W1l[128*136];
  __shared__ unsigned short W2l[128*136];
  __shared__ float cred[8*128], cred2[8*128];
  const int tid = threadIdx.x;
  const int row0 = blockIdx.x << 7;
  for (int i = tid; i < 128*17; i += 512) {
    int r = i / 17, c8 = (i - r*17) << 3;
    uint4 v = make_uint4(0,0,0,0);
    if (c8 < 128) v = *(const uint4*)(Ax + (size_t)(row0 + r)*128 + c8);
    *(uint4*)&Ab[r*136 + c8]  = v;
    *(uint4*)&W1l[r*136 + c8] = *(const uint4*)(W1t + r*136 + c8);
    *(uint4*)&W2l[r*136 + c8] = *(const uint4*)(W2t + r*136 + c8);
  }
  __syncthreads();
  const int wave = tid >> 6, lane = tid & 63;
  const int fr = lane & 15, fk = (lane >> 4) << 3;
  const int wrow = wave << 4;
  const int mrow = (lane >> 4) << 2;
  float b1v[8], b2v[8];
#pragma unroll
  for (int n = 0; n < 8; ++n) { b1v[n] = b1[(n<<4) + fr]; b2v[n] = b2[(n<<4) + fr]; }

  ffrag acc[8];
#pragma unroll
  for (int n = 0; n < 8; ++n) acc[n] = (ffrag){0.f,0.f,0.f,0.f};
#pragma unroll
  for (int s = 0; s < 4; ++s) {
    bfrag af = *(const bfrag*)&Ab[(wrow + fr)*136 + (s<<5) + fk];
#pragma unroll
    for (int n = 0; n < 8; ++n) {
      bfrag bf = *(const bfrag*)&W1l[((n<<4) + fr)*136 + (s<<5) + fk];
      acc[n] = __builtin_amdgcn_mfma_f32_16x16x32_bf16(af, bf, acc[n], 0, 0, 0);
    }
  }
#pragma unroll
  for (int n = 0; n < 8; ++n)
#pragma unroll
    for (int r = 0; r < 4; ++r) {
      float v = fmaxf(acc[n][r] + b1v[n], 0.f);
      Ab[(wrow + mrow + r)*136 + (n<<4) + fr] = f2b(v);
    }
  __syncthreads();

  ffrag acc2[8];
#pragma unroll
  for (int n = 0; n < 8; ++n) acc2[n] = (ffrag){0.f,0.f,0.f,0.f};
#pragma unroll
  for (int s = 0; s < 4; ++s) {
    bfrag af = *(const bfrag*)&Ab[(wrow + fr)*136 + (s<<5) + fk];
#pragma unroll
    for (int n = 0; n < 8; ++n) {
      bfrag bf = *(const bfrag*)&W2l[((n<<4) + fr)*136 + (s<<5) + fk];
      acc2[n] = __builtin_amdgcn_mfma_f32_16x16x32_bf16(af, bf, acc2[n], 0, 0, 0);
    }
  }
#pragma unroll
  for (int n = 0; n < 8; ++n) {
    float s = 0.f, q = 0.f;
#pragma unroll
    for (int r = 0; r < 4; ++r) {
      float v = fmaxf(acc2[n][r] + b2v[n], 0.f);
      outp[(size_t)(row0 + wrow + mrow + r)*128 + (n<<4) + fr] = v;
      s += v; q = fmaf(v, v, q);
    }
    s += __shfl_xor(s, 16); s += __shfl_xor(s, 32);
    q += __shfl_xor(q, 16); q += __shfl_xor(q, 32);
    if (lane < 16) { cred[wave*128 + (n<<4) + fr] = s; cred2[wave*128 + (n<<4) + fr] = q; }
  }
  __syncthreads();
  if (tid < 128) {
    float S = 0.f, Q = 0.f;
#pragma unroll
    for (int w = 0; w < 8; ++w) { S += cred[w*128 + tid]; Q += cred2[w*128 + tid]; }
    bnp[blockIdx.x*256 + tid] = S;
    bnp[blockIdx.x*256 + 128 + tid] = Q;
  }
}

// xd[b, L*128+f] = max_n affineBN(pre_L[b*40+n, f])
__global__ __launch_bounds__(128)
void k_drug_pool_bn(const float* __restrict__ p0, const float* __restrict__ p1,
                    const float* __restrict__ p2,
                    const float* __restrict__ s0, const float* __restrict__ s1,
                    const float* __restrict__ s2,
                    float* __restrict__ xd) {
  int b = blockIdx.x, f = threadIdx.x;
  const float* ps[3] = {p0,p1,p2};
  const float* ss[3] = {s0,s1,s2};
#pragma unroll
  for (int L = 0; L < 3; ++L) {
    float sc = ss[L][f], sh = ss[L][128+f];
    float m = -3.0e38f;
    const float* p = ps[L] + (size_t)b*40*128 + f;
    for (int n = 0; n < 40; ++n) m = fmaxf(m, fmaf(p[n*128], sc, sh));
    xd[(size_t)b*384 + L*128 + f] = m;
  }
}

// ===================== GEMM (f32, 64x64 tile) =====================
template<int ACT, int PART, int BNA, int NPA, int ACTA, int BNP>
__global__ __launch_bounds__(256)
void k_gemm(const float* __restrict__ A, int lda,
            const float* __restrict__ B, int ldb,
            const float* __restrict__ bias,
            float* __restrict__ C, int ldc, int Kchunk,
            long pstrideC, long pstrideA,
            const float* __restrict__ abias,
            const float* __restrict__ bnst,
            float* __restrict__ bnp) {
  __shared__ __align__(16) float As[32][68];
  __shared__ __align__(16) float Bs[32][68];
  const int tid = threadIdx.x;
  const int tx = tid & 15, ty = tid >> 4;
  const int row0 = blockIdx.y << 6, col0 = blockIdx.x << 6;
  const int kb = blockIdx.z * Kchunk;
  if (PART) C += (size_t)blockIdx.z * pstrideC;
  float acc[4][4] = {{0.f}};
  for (int k0 = 0; k0 < Kchunk; k0 += 32) {
#pragma unroll
    for (int i = 0; i < 2; ++i) {
      int idx = tid + (i << 8);
      int r = idx >> 3, c = (idx & 7) << 2;
      const float* ap = A + (size_t)(row0 + r)*lda + (kb + k0 + c);
      float4 v = *(const float4*)ap;
      if (NPA > 1) {
#pragma unroll
        for (int z = 1; z < NPA; ++z) {
          float4 p = *(const float4*)(ap + (size_t)z*pstrideA);
          v.x += p.x; v.y += p.y; v.z += p.z; v.w += p.w;
        }
        const float* ab = abias + (kb + k0 + c);
        v.x += ab[0]; v.y += ab[1]; v.z += ab[2]; v.w += ab[3];
        if (ACTA == 1) {
          v.x=fmaxf(v.x,0.f); v.y=fmaxf(v.y,0.f); v.z=fmaxf(v.z,0.f); v.w=fmaxf(v.w,0.f);
        } else if (ACTA == 2) {
          v.x = v.x>0.f?v.x:expm1f(v.x); v.y = v.y>0.f?v.y:expm1f(v.y);
          v.z = v.z>0.f?v.z:expm1f(v.z); v.w = v.w>0.f?v.w:expm1f(v.w);
        }
      }
      if (BNA) {
        int fb = (kb + k0 + c) & 15;
        float4 sc = *(const float4*)&bnst[fb];
        float4 sh = *(const float4*)&bnst[16 + fb];
        v.x = fmaf(v.x, sc.x, sh.x); v.y = fmaf(v.y, sc.y, sh.y);
        v.z = fmaf(v.z, sc.z, sh.z); v.w = fmaf(v.w, sc.w, sh.w);
      }
      int sw = ((c >> 2) & 7) << 2;
      int rs = r ^ sw;
      As[c+0][rs]=v.x; As[c+1][rs]=v.y; As[c+2][rs]=v.z; As[c+3][rs]=v.w;
    }
#pragma unroll
    for (int i = 0; i < 2; ++i) {
      int idx = tid + (i << 8);
      int r = idx >> 4, c = (idx & 15) << 2;
      *(float4*)&Bs[r][c] = *(const float4*)(B + (size_t)(kb + k0 + r)*ldb + (col0 + c));
    }
    __syncthreads();
#pragma unroll
    for (int kk = 0; kk < 32; ++kk) {
      int sw = ((kk >> 2) & 7) << 2;
      float4 av = *(const float4*)&As[kk][(ty << 2) ^ sw];
      float4 bv = *(const float4*)&Bs[kk][tx << 2];
      acc[0][0]=fmaf(av.x,bv.x,acc[0][0]); acc[0][1]=fmaf(av.x,bv.y,acc[0][1]);
      acc[0][2]=fmaf(av.x,bv.z,acc[0][2]); acc[0][3]=fmaf(av.x,bv.w,acc[0][3]);
      acc[1][0]=fmaf(av.y,bv.x,acc[1][0]); acc[1][1]=fmaf(av.y,bv.y,acc[1][1]);
      acc[1][2]=fmaf(av.y,bv.z,acc[1][2]); acc[1][3]=fmaf(av.y,bv.w,acc[1][3]);
      acc[2][0]=fmaf(av.z,bv.x,acc[2][0]); acc[2][1]=fmaf(av.z,bv.y,acc[2][1]);
      acc[2][2]=fmaf(av.z,bv.z,acc[2][2]); acc[2][3]=fmaf(av.z,bv.w,acc[2][3]);
      acc[3][0]=fmaf(av.w,bv.x,acc[3][0]); acc[3][1]=fmaf(av.w,bv.y,acc[3][1]);
      acc[3][2]=fmaf(av.w,bv.z,acc[3][2]); acc[3][3]=fmaf(av.w,bv.w,acc[3][3]);
    }
    __syncthreads();
  }
#pragma unroll
  for (int i = 0; i < 4; ++i) {
    int r = row0 + (ty<<2) + i, c = col0 + (tx<<2);
    float4 v = make_float4(acc[i][0], acc[i][1], acc[i][2], acc[i][3]);
    if (!PART) {
      if (bias) { v.x += bias[c]; v.y += bias[c+1]; v.z += bias[c+2]; v.w += bias[c+3]; }
      if (ACT == 1) { v.x=fmaxf(v.x,0.f); v.y=fmaxf(v.y,0.f); v.z=fmaxf(v.z,0.f); v.w=fmaxf(v.w,0.f); }
      else if (ACT == 2) {
        v.x = v.x>0.f?v.x:expm1f(v.x); v.y = v.y>0.f?v.y:expm1f(v.y);
        v.z = v.z>0.f?v.z:expm1f(v.z); v.w = v.w>0.f?v.w:expm1f(v.w);
      }
    }
    *(float4*)(C + (size_t)r*ldc + c) = v;
  }
}

template<int ACT>
__global__ void k_reduce(const float* __restrict__ parts, int np, long pstride,
                         const float* __restrict__ bias,
                         float* __restrict__ out, int ldo, int M, int N) {
  int t = blockIdx.x*blockDim.x + threadIdx.x;
  if (t >= M*N) return;
  int r = t / N, c = t - r*N;
  float s = 0.f;
  for (int z = 0; z < np; ++z) s += parts[(size_t)z*pstride + t];
  s += bias[c];
  if (ACT == 1) s = fmaxf(s, 0.f);
  else if (ACT == 2) s = s > 0.f ? s : expm1f(s);
  out[(size_t)r*ldo + c] = s;
}

// ===================== bf16 weight transpose (cemb1 B) =====================
__global__ __launch_bounds__(256)
void k_w2bt(const float* __restrict__ W, unsigned short* __restrict__ Bt) {
  __shared__ float tile[32][33];
  int bk = blockIdx.x << 5, bn = blockIdx.y << 5;
  int c = threadIdx.x & 31, r8 = threadIdx.x >> 5;
#pragma unroll
  for (int i = 0; i < 4; ++i) {
    int r = r8 + (i << 3);
    tile[r][c] = W[(size_t)(bk + r)*1024 + bn + c];
  }
  __syncthreads();
#pragma unroll
  for (int i = 0; i < 4; ++i) {
    int r = r8 + (i << 3);
    Bt[(size_t)(bn + r)*6400 + bk + c] = f2b(tile[c][r]);
  }
}

// ===================== MFMA bf16 GEMM: f32 A + BN inline, 128x128, split-K =====
__global__ __launch_bounds__(256)
void k_mfma128(const float* __restrict__ A,
               const unsigned short* __restrict__ Bt,
               const float* __restrict__ bnst,
               float* __restrict__ C, int ldc, int K,
               int Kchunk, long pstrideC) {
  __shared__ unsigned short Al[2][128*40];
  __shared__ unsigned short Bl[2][128*40];
  const int tid = threadIdx.x;
  const int row0 = blockIdx.y << 7, col0 = blockIdx.x << 7;
  const int kb = blockIdx.z * Kchunk;
  C += (size_t)blockIdx.z * pstrideC;
  const int wave = tid >> 6, lane = tid & 63;
  const int wr = wave >> 1, wc = wave & 1;
  const int fr = lane & 15, fk = (lane >> 4) << 3;
  const int lr = tid >> 1, lco = (tid & 1) << 4;

  float4 sc[4], sh[4];
#pragma unroll
  for (int i = 0; i < 4; ++i) {
    sc[i] = *(const float4*)&bnst[i*4];
    sh[i] = *(const float4*)&bnst[16 + i*4];
  }

  ffrag acc[4][4];
#pragma unroll
  for (int i = 0; i < 4; ++i)
#pragma unroll
    for (int n = 0; n < 4; ++n) acc[i][n] = (ffrag){0.f, 0.f, 0.f, 0.f};

  const float* ag = A + (size_t)(row0 + lr)*K + kb + lco;
  const unsigned short* bg = Bt + (size_t)(col0 + lr)*K + kb + lco;

  uint4 ra0, ra1;
  cvtbn16(ag, sc, sh, ra0, ra1);
  uint4 rb0 = *(const uint4*)bg, rb1 = *(const uint4*)(bg + 8);
  *(uint4*)&Al[0][lr*40 + lco] = ra0; *(uint4*)&Al[0][lr*40 + lco + 8] = ra1;
  *(uint4*)&Bl[0][lr*40 + lco] = rb0; *(uint4*)&Bl[0][lr*40 + lco + 8] = rb1;
  __syncthreads();

  const int NS = Kchunk >> 5;
  int cur = 0;
  for (int s = 0; s < NS; ++s) {
    if (s + 1 < NS) {
      cvtbn16(ag + ((s + 1) << 5), sc, sh, ra0, ra1);
      const unsigned short* bn = bg + ((s + 1) << 5);
      rb0 = *(const uint4*)bn; rb1 = *(const uint4*)(bn + 8);
    }
    bfrag af[4], bf[4];
#pragma unroll
    for (int i = 0; i < 4; ++i) af[i] = *(const bfrag*)&Al[cur][(wr*64 + i*16 + fr)*40 + fk];
#pragma unroll
    for (int n = 0; n < 4; ++n) bf[n] = *(const bfrag*)&Bl[cur][(wc*64 + n*16 + fr)*40 + fk];
#pragma unroll
    for (int i = 0; i < 4; ++i)
#pragma unroll
      for (int n = 0; n < 4; ++n)
        acc[i][n] = __builtin_amdgcn_mfma_f32_16x16x32_bf16(af[i], bf[n], acc[i][n], 0, 0, 0);
    if (s + 1 < NS) {
      cur ^= 1;
      *(uint4*)&Al[cur][lr*40 + lco] = ra0; *(uint4*)&Al[cur][lr*40 + lco + 8] = ra1;
      *(uint4*)&Bl[cur][lr*40 + lco] = rb0; *(uint4*)&Bl[cur][lr*40 + lco + 8] = rb1;
      __syncthreads();
    }
  }
  const int frow = (lane >> 4) << 2;
#pragma unroll
  for (int i = 0; i < 4; ++i)
#pragma unroll
    for (int n = 0; n < 4; ++n) {
      float* cp = C + (size_t)(row0 + wr*64 + i*16 + frow)*ldc + col0 + wc*64 + n*16 + fr;
#pragma unroll
      for (int r = 0; r < 4; ++r) cp[(size_t)r*ldc] = acc[i][n][r];
    }
}

// ===================== BN finalize: partials -> affine (scale, shift) =====================
__global__ void k_bn_fin(const float* __restrict__ parts, int nb, int C, float invn,
                         const float* __restrict__ g, const float* __restrict__ be,
                         float* __restrict__ stats) {
  int f = threadIdx.x;
  if (f >= C) return;
  float s = 0.f, s2 = 0.f;
#pragma unroll 4
  for (int z = 0; z < nb; ++z) { s += parts[z*2*C + f]; s2 += parts[z*2*C + C + f]; }
  float mu = s*invn;
  float var = fmaxf(s2*invn - mu*mu, 0.f);
  float rstd = rsqrtf(var + 1e-5f);
  float sc = g ? g[f]*rstd : rstd;
  stats[f] = sc;
  stats[C+f] = (be ? be[f] : 0.f) - mu*sc;
}

// ===================== fused per-batch GAT layer (round-16 gather order) =====================
template<int NODES, int NPOOL, int KIN, int MAXE, int SORTED, int BNIN, int NT>
__global__ __launch_bounds__(NT, 8)
void k_gat_lds(const float* __restrict__ x,
               const int* __restrict__ esrc, const int* __restrict__ edst, int Earg,
               const float* __restrict__ W, const float* __restrict__ as_,
               const float* __restrict__ ad_, const float* __restrict__ bias,
               const int* __restrict__ cluster,
               const float* __restrict__ instats,
               float* __restrict__ pooled, float* __restrict__ bnp) {
  constexpr int EIT = (MAXE + NT - 1) / NT;
  __shared__ unsigned int shp[NODES*9];   // h as packed bf16 pairs, stride 9
  __shared__ unsigned int spk[MAXE];
  __shared__ float sss[NODES], ssd[NODES];
  __shared__ int srow[NODES+1];
  __shared__ float sWl[KIN*16 + 16];
  __shared__ float sas[16], sad[16];
  __shared__ int schunk[32];
  __shared__ int sr2[2];
  const int b = blockIdx.x;
  const int tid = threadIdx.x;
  const int nbase = b*NODES;

  if (tid < KIN*16) sWl[tid] = W[tid];
  if (tid >= 64 && tid < 80)  sWl[KIN*16 + tid-64] = bias[tid-64];
  if (tid >= 80 && tid < 96)  sas[tid-80] = as_[tid-80];
  if (tid >= 96 && tid < 112) sad[tid-96] = ad_[tid-96];
  if (SORTED && tid == 0) {
    int a = 0, c = Earg;
    while (a < c) { int m = (a+c) >> 1; if (esrc[m] < nbase) a = m+1; else c = m; }
    sr2[0] = a;
    c = Earg;
    int nend = nbase + NODES;
    while (a < c) { int m = (a+c) >> 1; if (esrc[m] < nend) a = m+1; else c = m; }
    sr2[1] = a;
  }
  for (int i = tid; i <= NODES; i += NT) srow[i] = 0;
  __syncthreads();

  int e0, Eblk;
  if (SORTED) { e0 = sr2[0]; Eblk = sr2[1] - sr2[0]; }
  else        { e0 = b*Earg; Eblk = Earg; }

  int ers[EIT], erd[EIT];
#pragma unroll
  for (int it = 0; it < EIT; ++it) {
    int e = tid + it*NT;
    ers[it] = -1; erd[it] = -1;
    if (e < Eblk) {
      ers[it] = esrc[e0+e] - nbase;
      erd[it] = edst[e0+e] - nbase;
      atomicAdd(&srow[erd[it]+1], 1);
    }
  }
  // h = x@W; pack adjacent-feature pairs via shfl (f parity == lane parity)
  for (int i = tid; i < NODES*16; i += NT) {
    int n = i >> 4, f = i & 15;
    const float* xp = x + (size_t)(nbase + n)*KIN;
    float xq = (f < KIN) ? xp[f] : 0.f;
    if (BNIN && f < KIN) xq = fmaf(xq, instats[f], instats[16+f]);
    float hv = 0.f;
#pragma unroll
    for (int j = 0; j < KIN; ++j) hv = fmaf(__shfl(xq, j, 16), sWl[j*16 + f], hv);
    unsigned int hb = (unsigned int)f2b(hv);
    unsigned int partner = (unsigned int)__shfl_xor((int)hb, 1);
    if ((f & 1) == 0) shp[n*9 + (f >> 1)] = hb | (partner << 16);
    float s1 = hv * sas[f], s2 = hv * sad[f];
#pragma unroll
    for (int m = 8; m >= 1; m >>= 1) { s1 += __shfl_xor(s1, m); s2 += __shfl_xor(s2, m); }
    if (f == 0) { sss[n] = s1; ssd[n] = s2; }
  }
  __syncthreads();

  constexpr int NC = 32, CS = (NODES + NC - 1) / NC;
  if (tid < NC) {
    int run = 0, lo = tid*CS, hi = (tid+1)*CS < NODES ? (tid+1)*CS : NODES;
    for (int i = lo; i < hi; ++i) { run += srow[i+1]; srow[i+1] = run; }
    schunk[tid] = run;
  }
  __syncthreads();
  if (tid == 0) { int base = 0; for (int c = 0; c < NC; ++c) { int t2 = schunk[c]; schunk[c] = base; base += t2; } }
  __syncthreads();
  for (int i = tid; i < NODES; i += NT) srow[i+1] += schunk[i/CS];
  __syncthreads();

#pragma unroll
  for (int it = 0; it < EIT; ++it) {
    if (erd[it] >= 0) {
      int slot = atomicAdd(&srow[erd[it]], 1);
      float l = sss[ers[it]] + ssd[erd[it]];
      l = fmaxf(l, 0.2f*l);
      float ex = __expf(l);
      spk[slot] = ((__float_as_uint(ex) + 0x8000u) & 0xffff0000u) | (unsigned int)ers[it];
    }
  }
  __syncthreads();

  {
    const int lane = tid & 7, grp = tid >> 3;   // NT/8 node groups
    for (int n = grp; n < NODES; n += (NT >> 3)) {
      float ls = sss[n] + ssd[n];
      ls = fmaxf(ls, 0.2f*ls);
      float exs = __expf(ls);
      unsigned int hp = shp[n*9 + lane];
      float aLo = exs * b2f((unsigned short)hp);
      float aHi = exs * b2f((unsigned short)(hp >> 16));
      float sum = exs;
      int j = (n > 0) ? srow[n-1] : 0, j1 = srow[n];
      for (; j + 4 <= j1; j += 4) {
        unsigned int p0 = spk[j], p1 = spk[j+1], p2 = spk[j+2], p3 = spk[j+3];
        float e0 = __uint_as_float(p0 & 0xffff0000u);
        float e1 = __uint_as_float(p1 & 0xffff0000u);
        float e2 = __uint_as_float(p2 & 0xffff0000u);
        float e3 = __uint_as_float(p3 & 0xffff0000u);
        unsigned int h0 = shp[(p0 & 0xffffu)*9 + lane];
        unsigned int h1 = shp[(p1 & 0xffffu)*9 + lane];
        unsigned int h2 = shp[(p2 & 0xffffu)*9 + lane];
        unsigned int h3 = shp[(p3 & 0xffffu)*9 + lane];
        aLo = fmaf(e0, b2f((unsigned short)h0), aLo);
        aHi = fmaf(e0, b2f((unsigned short)(h0 >> 16)), aHi); sum += e0;
        aLo = fmaf(e1, b2f((unsigned short)h1), aLo);
        aHi = fmaf(e1, b2f((unsigned short)(h1 >> 16)), aHi); sum += e1;
        aLo = fmaf(e2, b2f((unsigned short)h2), aLo);
        aHi = fmaf(e2, b2f((unsigned short)(h2 >> 16)), aHi); sum += e2;
        aLo = fmaf(e3, b2f((unsigned short)h3), aLo);
        aHi = fmaf(e3, b2f((unsigned short)(h3 >> 16)), aHi); sum += e3;
      }
      for (; j < j1; ++j) {
        unsigned int p0 = spk[j];
        float e0 = __uint_as_float(p0 & 0xffff0000u);
        unsigned int h0 = shp[(p0 & 0xffffu)*9 + lane];
        aLo = fmaf(e0, b2f((unsigned short)h0), aLo);
        aHi = fmaf(e0, b2f((unsigned short)(h0 >> 16)), aHi); sum += e0;
      }
      float inv = 1.f / sum;
      float vLo = fmaxf(fmaf(aLo, inv, sWl[KIN*16 + 2*lane]), 0.f);
      float vHi = fmaxf(fmaf(aHi, inv, sWl[KIN*16 + 2*lane + 1]), 0.f);
      int* pp = (int*)pooled + (size_t)cluster[nbase + n]*16 + 2*lane;
      atomicMax(pp,     __float_as_int(vLo));
      atomicMax(pp + 1, __float_as_int(vHi));
    }
  }
  __syncthreads();   // drains this block's atomics (vmcnt(0) before barrier)

  // BN partials over this block's exclusive pooled slice
  {
    float s = 0.f, q = 0.f;
    const float* po = pooled + (size_t)b*NPOOL*16;
    int f = tid & 15;
    for (int r = tid >> 4; r < NPOOL; r += (NT >> 4)) {
      float v = po[r*16 + f];
      s += v; q = fmaf(v, v, q);
    }
    float* red = (float*)shp;          // >= 2*NT floats
    red[tid] = s; red[NT + tid] = q;
    __syncthreads();
    for (int o = NT >> 1; o >= 16; o >>= 1) {
      if (tid < o) { red[tid] += red[tid + o]; red[NT + tid] += red[NT + tid + o]; }
      __syncthreads();
    }
    if (tid < 16) { bnp[b*32 + tid] = red[tid]; bnp[b*32 + 16 + tid] = red[NT + tid]; }
  }
}

// ===================== final GEMV =====================
__global__ __launch_bounds__(64)
void k_gemv_out(const float* __restrict__ parts, long pstrideA,
                const float* __restrict__ abias,
                const float* __restrict__ w,
                const float* __restrict__ b, float* __restrict__ out) {
  int r = blockIdx.x, l = threadIdx.x;
  float s = 0.f;
  for (int k = l; k < 384; k += 64) {
    const float* p = parts + (size_t)r*384 + k;
    float h = p[0] + p[pstrideA] + p[2*pstrideA] + p[3*pstrideA] + abias[k];
    h = h > 0.f ? h : expm1f(h);
    s = fmaf(h, w[k], s);
  }
#pragma unroll
  for (int o = 32; o > 0; o >>= 1) s += __shfl_down(s, o);
  if (l == 0) out[r] = s + b[0];
}

// ===================== host orchestration =====================
extern "C" void kernel_launch(void* const* d_in, const int* in_sizes, int n_in,
                              void* d_out, int out_size, void* d_ws, size_t ws_size,
                              hipStream_t stream) {
  (void)n_in; (void)out_size;
  const int B = 512;
  const int nd  = B*40;
  const int nc1 = B*512;
  const int nc2 = B*400;
  const int Ec0 = in_sizes[42]/2;
  const int Ec1 = in_sizes[43]/2;

  const float* drug_x = (const float*)d_in[0];
  const float* cell_x = (const float*)d_in[1];
  const float* gW1[3] = {(const float*)d_in[2],(const float*)d_in[8],(const float*)d_in[14]};
  const float* gb1[3] = {(const float*)d_in[3],(const float*)d_in[9],(const float*)d_in[15]};
  const float* gW2[3] = {(const float*)d_in[4],(const float*)d_in[10],(const float*)d_in[16]};
  const float* gb2[3] = {(const float*)d_in[5],(const float*)d_in[11],(const float*)d_in[17]};
  const float* gg [3] = {(const float*)d_in[6],(const float*)d_in[12],(const float*)d_in[18]};
  const float* gbe[3] = {(const float*)d_in[7],(const float*)d_in[13],(const float*)d_in[19]};
  const float* demb_W = (const float*)d_in[20]; const float* demb_b = (const float*)d_in[21];
  const float* gatW[2]  = {(const float*)d_in[22],(const float*)d_in[26]};
  const float* gatAS[2] = {(const float*)d_in[23],(const float*)d_in[27]};
  const float* gatAD[2] = {(const float*)d_in[24],(const float*)d_in[28]};
  const float* gatB[2]  = {(const float*)d_in[25],(const float*)d_in[29]};
  const float* cembW1 = (const float*)d_in[30]; const float* cembb1 = (const float*)d_in[31];
  const float* cembW2 = (const float*)d_in[32]; const float* cembb2 = (const float*)d_in[33];
  const float* regW1 = (const float*)d_in[34]; const float* regb1 = (const float*)d_in[35];
  const float* regW2 = (const float*)d_in[36]; const float* regb2 = (const float*)d_in[37];
  const float* regW3 = (const float*)d_in[38]; const float* regb3 = (const float*)d_in[39];
  const int* dei = (const int*)d_in[40];
  const int* ei0 = (const int*)d_in[42];
  const int* ei1 = (const int*)d_in[43];
  const int* cl0 = (const int*)d_in[44];
  const int* cl1 = (const int*)d_in[45];
  const int Ed  = in_sizes[40]/2;
  const int *dsrc = dei, *ddst = dei + Ed;
  const int *src0 = ei0, *dst0 = ei0 + Ec0;
  const int *src1 = ei1, *dst1 = ei1 + Ec1;
  float* out = (float*)d_out;

  // ---- workspace layout ----
  char* base = (char*)d_ws; size_t off = 0;
  auto AL = [&](size_t bytes)->char* { char* p = base + off; off = (off + bytes + 255) & ~(size_t)255; return p; };
  float* h_cat   = (float*)AL((size_t)512*384*4);
  float* xd      = (float*)AL((size_t)512*384*4);
  float* pooled1 = (float*)AL((size_t)nc1*16*4);
  float* pooled2 = (float*)AL((size_t)nc2*16*4);
  float* st_g0   = (float*)AL(256*4);
  float* st_g1   = (float*)AL(256*4);
  float* st_g2   = (float*)AL(256*4);
  float* st16_0  = (float*)AL(32*4);
  float* st16_1  = (float*)AL(32*4);
  float* bparts  = (float*)AL((size_t)512*256*4);
  unsigned short* Wt6 = (unsigned short*)AL((size_t)6*128*136*2);
  char*  S       = base + off;
  if (ws_size < off + (size_t)53*1024*1024) return;

  dim3 b256(256);

  // drug-phase scratch (S)
  float* pre0 = (float*)(S);
  float* pre1 = pre0 + (size_t)nd*128;
  float* pre2 = pre1 + (size_t)nd*128;
  unsigned short* xin_b = (unsigned short*)(pre2 + (size_t)nd*128);
  float* pre[3] = {pre0, pre1, pre2};
  float* stg[3] = {st_g0, st_g1, st_g2};

  // cell-phase scratch (S, reused after drug pool)
  size_t so = 0;
  auto SB = [&](size_t bytes)->char* { char* p = S + so; so = (so + bytes + 255) & ~(size_t)255; return p; };
  unsigned short* Btb = (unsigned short*)SB((size_t)1024*6400*2);
  float* parts1 = (float*)SB((size_t)8*512*1024*4);
  float* parts2 = (float*)SB((size_t)8*512*256*4);
  float* partsA = (float*)SB((size_t)4*512*384*4);
  float* partsB = (float*)SB((size_t)4*512*384*4);
  float* cembh  = (float*)SB((size_t)512*1024*4);

  // ================= DRUG BRANCH (bf16 MFMA GIN) =================
  k_w2bt6<<<dim3(68, 6), b256, 0, stream>>>(gW1[0], gW1[1], gW1[2],
                                            gW2[0], gW2[1], gW2[2], Wt6);
  for (int L = 0; L < 3; ++L) {
    if (L == 0)
      k_gin_agg_b<77,0><<<dim3(512), b256, 0, stream>>>(drug_x, nullptr, dsrc, ddst, xin_b);
    else
      k_gin_agg_b<128,1><<<dim3(512), b256, 0, stream>>>(pre[L-1], stg[L-1], dsrc, ddst, xin_b);
    k_gin_fmfma<<<dim3(160), dim3(512), 0, stream>>>(
        xin_b, Wt6 + (size_t)L*128*136, Wt6 + (size_t)(3+L)*128*136,
        gb1[L], gb2[L], pre[L], bparts);
    k_bn_fin<<<dim3(1), dim3(128), 0, stream>>>(bparts, 160, 128, 1.f/nd, gg[L], gbe[L], stg[L]);
  }
  k_drug_pool_bn<<<dim3(512), dim3(128), 0, stream>>>(pre0, pre1, pre2, st_g0, st_g1, st_g2, xd);
  k_gemm<1,0,0,0,0,0><<<dim3(2,8,1), b256, 0, stream>>>(
      xd, 384, demb_W, 128, demb_b, h_cat, 384, 384, 0, 0, nullptr, nullptr, nullptr);

  // cembW1 -> bf16 transposed (drug scratch dead now)
  k_w2bt<<<dim3(200, 32), b256, 0, stream>>>(cembW1, Btb);

  // ================= CELL BRANCH: two fused GAT layers =================
  k_gat_lds<706,512,3,8000,0,0,1024><<<dim3(512), dim3(1024), 0, stream>>>(
      cell_x, src0, dst0, Ec0/512, gatW[0], gatAS[0], gatAD[0], gatB[0], cl0,
      nullptr, pooled1, bparts);
  k_bn_fin<<<dim3(1), dim3(16), 0, stream>>>(bparts, 512, 16, 1.f/nc1, nullptr, nullptr, st16_0);

  k_gat_lds<512,400,16,8000,1,1,1024><<<dim3(512), dim3(1024), 0, stream>>>(
      pooled1, src1, dst1, Ec1, gatW[1], gatAS[1], gatAD[1], gatB[1], cl1,
      st16_0, pooled2, bparts);
  k_bn_fin<<<dim3(1), dim3(16), 0, stream>>>(bparts, 512, 16, 1.f/nc2, nullptr, nullptr, st16_1);

  // ================= cell embedding MLP (BN+bf16 fused into MFMA A-staging) =====
  k_mfma128<<<dim3(8, 4, 8), b256, 0, stream>>>(
      pooled2, Btb, st16_1, parts1, 1024, 6400, 800, (long)512*1024);
  k_reduce<1><<<dim3((512*1024+255)/256), b256, 0, stream>>>(
      parts1, 8, (long)512*1024, cembb1, cembh, 1024, 512, 1024);
  k_gemm<0,1,0,0,0,0><<<dim3(4,8,8), b256, 0, stream>>>(
      cembh, 1024, cembW2, 256, nullptr, parts2, 256, 128,
      (long)512*256, 0, nullptr, nullptr, nullptr);
  k_reduce<1><<<dim3((512*256+255)/256), b256, 0, stream>>>(
      parts2, 8, (long)512*256, cembb2, h_cat + 128, 384, 512, 256);

  // ================= regressor =================
  k_gemm<0,1,0,0,0,0><<<dim3(6,8,4), b256, 0, stream>>>(
      h_cat, 384, regW1, 384, nullptr, partsA, 384, 96,
      (long)512*384, 0, nullptr, nullptr, nullptr);
  k_gemm<0,1,0,4,2,0><<<dim3(6,8,4), b256, 0, stream>>>(
      partsA, 384, regW2, 384, nullptr, partsB, 384, 96,
      (long)512*384, (long)512*384, regb1, nullptr, nullptr);
  k_gemv_out<<<dim3(512), dim3(64), 0, stream>>>(
      partsB, (long)512*384, regb2, regW3, regb3, out);
}

// Round 21
// 429.395 us; speedup vs baseline: 1.0225x; 1.0186x over previous
//
#include <hip/hip_runtime.h>
#include <math.h>

typedef __attribute__((ext_vector_type(8))) short bfrag;
typedef __attribute__((ext_vector_type(4))) float ffrag;

__device__ __forceinline__ unsigned short f2b(float v) {
  return (unsigned short)((__float_as_uint(v) + 0x8000u) >> 16);
}
__device__ __forceinline__ float b2f(unsigned short u) {
  return __uint_as_float((unsigned int)u << 16);
}

// ===================== batched weight transpose -> bf16 [128][136] =====================
__global__ __launch_bounds__(256)
void k_w2bt6(const float* __restrict__ w0, const float* __restrict__ w1,
             const float* __restrict__ w2, const float* __restrict__ w3,
             const float* __restrict__ w4, const float* __restrict__ w5,
             unsigned short* __restrict__ out) {
  int t = blockIdx.x*256 + threadIdx.x;
  if (t >= 128*136) return;
  int L = blockIdx.y;
  const float* W; int Ksrc = 128;
  switch (L) {
    case 0: W = w0; Ksrc = 77; break;
    case 1: W = w1; break;
    case 2: W = w2; break;
    case 3: W = w3; break;
    case 4: W = w4; break;
    default: W = w5; break;
  }
  int n = t / 136, k = t - n*136;
  float v = (k < Ksrc) ? W[(size_t)k*128 + n] : 0.f;
  out[(size_t)L*128*136 + t] = f2b(v);
}

// ===================== per-batch GIN aggregation -> bf16 (in-LDS CSR) =====================
template<int KIN, int BNIN>
__global__ __launch_bounds__(256)
void k_gin_agg_b(const float* __restrict__ xg, const float* __restrict__ st,
                 const int* __restrict__ esrc, const int* __restrict__ edst,
                 unsigned short* __restrict__ xin) {
  __shared__ float xb[40*128];
  __shared__ unsigned short scsr[160];
  __shared__ int srow[41];
  const int b = blockIdx.x, tid = threadIdx.x, nbase = b*40;
  if (tid <= 40) srow[tid] = 0;
  __syncthreads();
  int rs = -1, rd = -1;
  if (tid < 160) {
    rs = esrc[b*160+tid] - nbase;
    rd = edst[b*160+tid] - nbase;
    atomicAdd(&srow[rd+1], 1);
  }
  for (int i = tid; i < 40*KIN; i += 256) {
    int n = i/KIN, f = i - n*KIN;
    float v = xg[(size_t)(nbase+n)*KIN + f];
    if (BNIN) v = fmaf(v, st[f], st[KIN+f]);
    xb[n*128 + f] = v;
  }
  __syncthreads();
  if (tid == 0) { int run = 0; for (int i = 1; i <= 40; ++i) { run += srow[i]; srow[i] = run; } }
  __syncthreads();
  if (tid < 160) { int slot = atomicAdd(&srow[rd], 1); scsr[slot] = (unsigned short)rs; }
  __syncthreads();
  for (int i = tid; i < 40*128; i += 256) {
    int n = i >> 7, f = i & 127;
    float a = 0.f;
    if (f < KIN) {
      a = xb[n*128 + f];
      int j0 = n ? srow[n-1] : 0, j1 = srow[n];
      for (int j = j0; j < j1; ++j) a += xb[scsr[j]*128 + f];
    }
    xin[(size_t)nbase*128 + i] = f2b(a);
  }
}

// ===================== fused GIN layer via MFMA =====================
__global__ __launch_bounds__(512)
void k_gin_fmfma(const unsigned short* __restrict__ Ax,
                 const unsigned short* __restrict__ W1t,
                 const unsigned short* __restrict__ W2t,
                 const float* __restrict__ b1, const float* __restrict__ b2,
                 float* __restrict__ outp, float* __restrict__ bnp) {
  __shared__ unsigned short Ab[128*136];
  __shared__ unsigned short W1l[128*136];
  __shared__ unsigned short W2l[128*136];
  __shared__ float cred[8*128], cred2[8*128];
  const int tid = threadIdx.x;
  const int row0 = blockIdx.x << 7;
  for (int i = tid; i < 128*17; i += 512) {
    int r = i / 17, c8 = (i - r*17) << 3;
    uint4 v = make_uint4(0,0,0,0);
    if (c8 < 128) v = *(const uint4*)(Ax + (size_t)(row0 + r)*128 + c8);
    *(uint4*)&Ab[r*136 + c8]  = v;
    *(uint4*)&W1l[r*136 + c8] = *(const uint4*)(W1t + r*136 + c8);
    *(uint4*)&W2l[r*136 + c8] = *(const uint4*)(W2t + r*136 + c8);
  }
  __syncthreads();
  const int wave = tid >> 6, lane = tid & 63;
  const int fr = lane & 15, fk = (lane >> 4) << 3;
  const int wrow = wave << 4;
  const int mrow = (lane >> 4) << 2;
  float b1v[8], b2v[8];
#pragma unroll
  for (int n = 0; n < 8; ++n) { b1v[n] = b1[(n<<4) + fr]; b2v[n] = b2[(n<<4) + fr]; }

  ffrag acc[8];
#pragma unroll
  for (int n = 0; n < 8; ++n) acc[n] = (ffrag){0.f,0.f,0.f,0.f};
#pragma unroll
  for (int s = 0; s < 4; ++s) {
    bfrag af = *(const bfrag*)&Ab[(wrow + fr)*136 + (s<<5) + fk];
#pragma unroll
    for (int n = 0; n < 8; ++n) {
      bfrag bf = *(const bfrag*)&W1l[((n<<4) + fr)*136 + (s<<5) + fk];
      acc[n] = __builtin_amdgcn_mfma_f32_16x16x32_bf16(af, bf, acc[n], 0, 0, 0);
    }
  }
#pragma unroll
  for (int n = 0; n < 8; ++n)
#pragma unroll
    for (int r = 0; r < 4; ++r) {
      float v = fmaxf(acc[n][r] + b1v[n], 0.f);
      Ab[(wrow + mrow + r)*136 + (n<<4) + fr] = f2b(v);
    }
  __syncthreads();

  ffrag acc2[8];
#pragma unroll
  for (int n = 0; n < 8; ++n) acc2[n] = (ffrag){0.f,0.f,0.f,0.f};
#pragma unroll
  for (int s = 0; s < 4; ++s) {
    bfrag af = *(const bfrag*)&Ab[(wrow + fr)*136 + (s<<5) + fk];
#pragma unroll
    for (int n = 0; n < 8; ++n) {
      bfrag bf = *(const bfrag*)&W2l[((n<<4) + fr)*136 + (s<<5) + fk];
      acc2[n] = __builtin_amdgcn_mfma_f32_16x16x32_bf16(af, bf, acc2[n], 0, 0, 0);
    }
  }
#pragma unroll
  for (int n = 0; n < 8; ++n) {
    float s = 0.f, q = 0.f;
#pragma unroll
    for (int r = 0; r < 4; ++r) {
      float v = fmaxf(acc2[n][r] + b2v[n], 0.f);
      outp[(size_t)(row0 + wrow + mrow + r)*128 + (n<<4) + fr] = v;
      s += v; q = fmaf(v, v, q);
    }
    s += __shfl_xor(s, 16); s += __shfl_xor(s, 32);
    q += __shfl_xor(q, 16); q += __shfl_xor(q, 32);
    if (lane < 16) { cred[wave*128 + (n<<4) + fr] = s; cred2[wave*128 + (n<<4) + fr] = q; }
  }
  __syncthreads();
  if (tid < 128) {
    float S = 0.f, Q = 0.f;
#pragma unroll
    for (int w = 0; w < 8; ++w) { S += cred[w*128 + tid]; Q += cred2[w*128 + tid]; }
    bnp[blockIdx.x*256 + tid] = S;
    bnp[blockIdx.x*256 + 128 + tid] = Q;
  }
}

// xd[b, L*128+f] = max_n affineBN(pre_L[b*40+n, f])
__global__ __launch_bounds__(128)
void k_drug_pool_bn(const float* __restrict__ p0, const float* __restrict__ p1,
                    const float* __restrict__ p2,
                    const float* __restrict__ s0, const float* __restrict__ s1,
                    const float* __restrict__ s2,
                    float* __restrict__ xd) {
  int b = blockIdx.x, f = threadIdx.x;
  const float* ps[3] = {p0,p1,p2};
  const float* ss[3] = {s0,s1,s2};
#pragma unroll
  for (int L = 0; L < 3; ++L) {
    float sc = ss[L][f], sh = ss[L][128+f];
    float m = -3.0e38f;
    const float* p = ps[L] + (size_t)b*40*128 + f;
    for (int n = 0; n < 40; ++n) m = fmaxf(m, fmaf(p[n*128], sc, sh));
    xd[(size_t)b*384 + L*128 + f] = m;
  }
}

// ===================== GEMM (f32, 64x64 tile) =====================
template<int ACT, int PART, int BNA, int NPA, int ACTA, int BNP>
__global__ __launch_bounds__(256)
void k_gemm(const float* __restrict__ A, int lda,
            const float* __restrict__ B, int ldb,
            const float* __restrict__ bias,
            float* __restrict__ C, int ldc, int Kchunk,
            long pstrideC, long pstrideA,
            const float* __restrict__ abias,
            const float* __restrict__ bnst,
            float* __restrict__ bnp) {
  __shared__ __align__(16) float As[32][68];
  __shared__ __align__(16) float Bs[32][68];
  const int tid = threadIdx.x;
  const int tx = tid & 15, ty = tid >> 4;
  const int row0 = blockIdx.y << 6, col0 = blockIdx.x << 6;
  const int kb = blockIdx.z * Kchunk;
  if (PART) C += (size_t)blockIdx.z * pstrideC;
  float acc[4][4] = {{0.f}};
  for (int k0 = 0; k0 < Kchunk; k0 += 32) {
#pragma unroll
    for (int i = 0; i < 2; ++i) {
      int idx = tid + (i << 8);
      int r = idx >> 3, c = (idx & 7) << 2;
      const float* ap = A + (size_t)(row0 + r)*lda + (kb + k0 + c);
      float4 v = *(const float4*)ap;
      if (NPA > 1) {
#pragma unroll
        for (int z = 1; z < NPA; ++z) {
          float4 p = *(const float4*)(ap + (size_t)z*pstrideA);
          v.x += p.x; v.y += p.y; v.z += p.z; v.w += p.w;
        }
        const float* ab = abias + (kb + k0 + c);
        v.x += ab[0]; v.y += ab[1]; v.z += ab[2]; v.w += ab[3];
        if (ACTA == 1) {
          v.x=fmaxf(v.x,0.f); v.y=fmaxf(v.y,0.f); v.z=fmaxf(v.z,0.f); v.w=fmaxf(v.w,0.f);
        } else if (ACTA == 2) {
          v.x = v.x>0.f?v.x:expm1f(v.x); v.y = v.y>0.f?v.y:expm1f(v.y);
          v.z = v.z>0.f?v.z:expm1f(v.z); v.w = v.w>0.f?v.w:expm1f(v.w);
        }
      }
      if (BNA) {
        int fb = (kb + k0 + c) & 15;
        float4 sc = *(const float4*)&bnst[fb];
        float4 sh = *(const float4*)&bnst[16 + fb];
        v.x = fmaf(v.x, sc.x, sh.x); v.y = fmaf(v.y, sc.y, sh.y);
        v.z = fmaf(v.z, sc.z, sh.z); v.w = fmaf(v.w, sc.w, sh.w);
      }
      int sw = ((c >> 2) & 7) << 2;
      int rs = r ^ sw;
      As[c+0][rs]=v.x; As[c+1][rs]=v.y; As[c+2][rs]=v.z; As[c+3][rs]=v.w;
    }
#pragma unroll
    for (int i = 0; i < 2; ++i) {
      int idx = tid + (i << 8);
      int r = idx >> 4, c = (idx & 15) << 2;
      *(float4*)&Bs[r][c] = *(const float4*)(B + (size_t)(kb + k0 + r)*ldb + (col0 + c));
    }
    __syncthreads();
#pragma unroll
    for (int kk = 0; kk < 32; ++kk) {
      int sw = ((kk >> 2) & 7) << 2;
      float4 av = *(const float4*)&As[kk][(ty << 2) ^ sw];
      float4 bv = *(const float4*)&Bs[kk][tx << 2];
      acc[0][0]=fmaf(av.x,bv.x,acc[0][0]); acc[0][1]=fmaf(av.x,bv.y,acc[0][1]);
      acc[0][2]=fmaf(av.x,bv.z,acc[0][2]); acc[0][3]=fmaf(av.x,bv.w,acc[0][3]);
      acc[1][0]=fmaf(av.y,bv.x,acc[1][0]); acc[1][1]=fmaf(av.y,bv.y,acc[1][1]);
      acc[1][2]=fmaf(av.y,bv.z,acc[1][2]); acc[1][3]=fmaf(av.y,bv.w,acc[1][3]);
      acc[2][0]=fmaf(av.z,bv.x,acc[2][0]); acc[2][1]=fmaf(av.z,bv.y,acc[2][1]);
      acc[2][2]=fmaf(av.z,bv.z,acc[2][2]); acc[2][3]=fmaf(av.z,bv.w,acc[2][3]);
      acc[3][0]=fmaf(av.w,bv.x,acc[3][0]); acc[3][1]=fmaf(av.w,bv.y,acc[3][1]);
      acc[3][2]=fmaf(av.w,bv.z,acc[3][2]); acc[3][3]=fmaf(av.w,bv.w,acc[3][3]);
    }
    __syncthreads();
  }
#pragma unroll
  for (int i = 0; i < 4; ++i) {
    int r = row0 + (ty<<2) + i, c = col0 + (tx<<2);
    float4 v = make_float4(acc[i][0], acc[i][1], acc[i][2], acc[i][3]);
    if (!PART) {
      if (bias) { v.x += bias[c]; v.y += bias[c+1]; v.z += bias[c+2]; v.w += bias[c+3]; }
      if (ACT == 1) { v.x=fmaxf(v.x,0.f); v.y=fmaxf(v.y,0.f); v.z=fmaxf(v.z,0.f); v.w=fmaxf(v.w,0.f); }
      else if (ACT == 2) {
        v.x = v.x>0.f?v.x:expm1f(v.x); v.y = v.y>0.f?v.y:expm1f(v.y);
        v.z = v.z>0.f?v.z:expm1f(v.z); v.w = v.w>0.f?v.w:expm1f(v.w);
      }
    }
    *(float4*)(C + (size_t)r*ldc + c) = v;
  }
}

template<int ACT>
__global__ void k_reduce(const float* __restrict__ parts, int np, long pstride,
                         const float* __restrict__ bias,
                         float* __restrict__ out, int ldo, int M, int N) {
  int t = blockIdx.x*blockDim.x + threadIdx.x;
  if (t >= M*N) return;
  int r = t / N, c = t - r*N;
  float s = 0.f;
  for (int z = 0; z < np; ++z) s += parts[(size_t)z*pstride + t];
  s += bias[c];
  if (ACT == 1) s = fmaxf(s, 0.f);
  else if (ACT == 2) s = s > 0.f ? s : expm1f(s);
  out[(size_t)r*ldo + c] = s;
}

// ===================== bf16 conversion kernels (cemb1 MFMA path) =====================
__global__ __launch_bounds__(256)
void k_w2bt(const float* __restrict__ W, unsigned short* __restrict__ Bt) {
  __shared__ float tile[32][33];
  int bk = blockIdx.x << 5, bn = blockIdx.y << 5;
  int c = threadIdx.x & 31, r8 = threadIdx.x >> 5;
#pragma unroll
  for (int i = 0; i < 4; ++i) {
    int r = r8 + (i << 3);
    tile[r][c] = W[(size_t)(bk + r)*1024 + bn + c];
  }
  __syncthreads();
#pragma unroll
  for (int i = 0; i < 4; ++i) {
    int r = r8 + (i << 3);
    Bt[(size_t)(bn + r)*6400 + bk + c] = f2b(tile[c][r]);
  }
}

__global__ void k_a2bn(const float* __restrict__ x, const float* __restrict__ st,
                       unsigned short* __restrict__ o, int total4) {
  int t = blockIdx.x*blockDim.x + threadIdx.x;
  if (t >= total4) return;
  int fb = (t << 2) & 15;
  float4 v = *(const float4*)(x + ((size_t)t << 2));
  float4 sc = *(const float4*)&st[fb];
  float4 sh = *(const float4*)&st[16 + fb];
  ushort4 r;
  r.x = f2b(fmaf(v.x, sc.x, sh.x));
  r.y = f2b(fmaf(v.y, sc.y, sh.y));
  r.z = f2b(fmaf(v.z, sc.z, sh.z));
  r.w = f2b(fmaf(v.w, sc.w, sh.w));
  *(ushort4*)(o + ((size_t)t << 2)) = r;
}

// ===================== MFMA bf16 GEMM: 128x128 tile, split-K partials =====================
__global__ __launch_bounds__(256)
void k_mfma128(const unsigned short* __restrict__ A,
               const unsigned short* __restrict__ Bt,
               float* __restrict__ C, int ldc, int K,
               int Kchunk, long pstrideC) {
  __shared__ unsigned short Al[2][128*40];
  __shared__ unsigned short Bl[2][128*40];
  const int tid = threadIdx.x;
  const int row0 = blockIdx.y << 7, col0 = blockIdx.x << 7;
  const int kb = blockIdx.z * Kchunk;
  C += (size_t)blockIdx.z * pstrideC;
  const int wave = tid >> 6, lane = tid & 63;
  const int wr = wave >> 1, wc = wave & 1;
  const int fr = lane & 15, fk = (lane >> 4) << 3;
  const int lr = tid >> 1, lco = (tid & 1) << 4;

  ffrag acc[4][4];
#pragma unroll
  for (int i = 0; i < 4; ++i)
#pragma unroll
    for (int n = 0; n < 4; ++n) acc[i][n] = (ffrag){0.f, 0.f, 0.f, 0.f};

  const unsigned short* ag = A  + (size_t)(row0 + lr)*K + kb + lco;
  const unsigned short* bg = Bt + (size_t)(col0 + lr)*K + kb + lco;

  uint4 ra0 = *(const uint4*)ag, ra1 = *(const uint4*)(ag + 8);
  uint4 rb0 = *(const uint4*)bg, rb1 = *(const uint4*)(bg + 8);
  *(uint4*)&Al[0][lr*40 + lco] = ra0; *(uint4*)&Al[0][lr*40 + lco + 8] = ra1;
  *(uint4*)&Bl[0][lr*40 + lco] = rb0; *(uint4*)&Bl[0][lr*40 + lco + 8] = rb1;
  __syncthreads();

  const int NS = Kchunk >> 5;
  int cur = 0;
  for (int s = 0; s < NS; ++s) {
    if (s + 1 < NS) {
      const unsigned short* an = ag + ((s + 1) << 5);
      const unsigned short* bn = bg + ((s + 1) << 5);
      ra0 = *(const uint4*)an; ra1 = *(const uint4*)(an + 8);
      rb0 = *(const uint4*)bn; rb1 = *(const uint4*)(bn + 8);
    }
    bfrag af[4], bf[4];
#pragma unroll
    for (int i = 0; i < 4; ++i) af[i] = *(const bfrag*)&Al[cur][(wr*64 + i*16 + fr)*40 + fk];
#pragma unroll
    for (int n = 0; n < 4; ++n) bf[n] = *(const bfrag*)&Bl[cur][(wc*64 + n*16 + fr)*40 + fk];
#pragma unroll
    for (int i = 0; i < 4; ++i)
#pragma unroll
      for (int n = 0; n < 4; ++n)
        acc[i][n] = __builtin_amdgcn_mfma_f32_16x16x32_bf16(af[i], bf[n], acc[i][n], 0, 0, 0);
    if (s + 1 < NS) {
      cur ^= 1;
      *(uint4*)&Al[cur][lr*40 + lco] = ra0; *(uint4*)&Al[cur][lr*40 + lco + 8] = ra1;
      *(uint4*)&Bl[cur][lr*40 + lco] = rb0; *(uint4*)&Bl[cur][lr*40 + lco + 8] = rb1;
      __syncthreads();
    }
  }
  const int frow = (lane >> 4) << 2;
#pragma unroll
  for (int i = 0; i < 4; ++i)
#pragma unroll
    for (int n = 0; n < 4; ++n) {
      float* cp = C + (size_t)(row0 + wr*64 + i*16 + frow)*ldc + col0 + wc*64 + n*16 + fr;
#pragma unroll
      for (int r = 0; r < 4; ++r) cp[(size_t)r*ldc] = acc[i][n][r];
    }
}

// ===================== BN finalize: partials -> affine (scale, shift) =====================
__global__ void k_bn_fin(const float* __restrict__ parts, int nb, int C, float invn,
                         const float* __restrict__ g, const float* __restrict__ be,
                         float* __restrict__ stats) {
  int f = threadIdx.x;
  if (f >= C) return;
  float s = 0.f, s2 = 0.f;
#pragma unroll 4
  for (int z = 0; z < nb; ++z) { s += parts[z*2*C + f]; s2 += parts[z*2*C + C + f]; }
  float mu = s*invn;
  float var = fmaxf(s2*invn - mu*mu, 0.f);
  float rstd = rsqrtf(var + 1e-5f);
  float sc = g ? g[f]*rstd : rstd;
  stats[f] = sc;
  stats[C+f] = (be ? be[f] : 0.f) - mu*sc;
}

// ===================== fused per-batch GAT layer (round-16 best config) =====================
// 1024 threads (16 waves -> 32 waves/CU at 2 blocks/CU); h packed as bf16
// pairs (8 lanes/node, one 4B LDS read -> 2 features); natural gather order;
// BN partials computed in-kernel over the block's exclusive pooled slice.
template<int NODES, int NPOOL, int KIN, int MAXE, int SORTED, int BNIN, int NT>
__global__ __launch_bounds__(NT, 8)
void k_gat_lds(const float* __restrict__ x,
               const int* __restrict__ esrc, const int* __restrict__ edst, int Earg,
               const float* __restrict__ W, const float* __restrict__ as_,
               const float* __restrict__ ad_, const float* __restrict__ bias,
               const int* __restrict__ cluster,
               const float* __restrict__ instats,
               float* __restrict__ pooled, float* __restrict__ bnp) {
  constexpr int EIT = (MAXE + NT - 1) / NT;
  __shared__ unsigned int shp[NODES*9];   // h as packed bf16 pairs, stride 9
  __shared__ unsigned int spk[MAXE];
  __shared__ float sss[NODES], ssd[NODES];
  __shared__ int srow[NODES+1];
  __shared__ float sWl[KIN*16 + 16];
  __shared__ float sas[16], sad[16];
  __shared__ int schunk[32];
  __shared__ int sr2[2];
  const int b = blockIdx.x;
  const int tid = threadIdx.x;
  const int nbase = b*NODES;

  if (tid < KIN*16) sWl[tid] = W[tid];
  if (tid >= 64 && tid < 80)  sWl[KIN*16 + tid-64] = bias[tid-64];
  if (tid >= 80 && tid < 96)  sas[tid-80] = as_[tid-80];
  if (tid >= 96 && tid < 112) sad[tid-96] = ad_[tid-96];
  if (SORTED && tid == 0) {
    int a = 0, c = Earg;
    while (a < c) { int m = (a+c) >> 1; if (esrc[m] < nbase) a = m+1; else c = m; }
    sr2[0] = a;
    c = Earg;
    int nend = nbase + NODES;
    while (a < c) { int m = (a+c) >> 1; if (esrc[m] < nend) a = m+1; else c = m; }
    sr2[1] = a;
  }
  for (int i = tid; i <= NODES; i += NT) srow[i] = 0;
  __syncthreads();

  int e0, Eblk;
  if (SORTED) { e0 = sr2[0]; Eblk = sr2[1] - sr2[0]; }
  else        { e0 = b*Earg; Eblk = Earg; }

  int ers[EIT], erd[EIT];
#pragma unroll
  for (int it = 0; it < EIT; ++it) {
    int e = tid + it*NT;
    ers[it] = -1; erd[it] = -1;
    if (e < Eblk) {
      ers[it] = esrc[e0+e] - nbase;
      erd[it] = edst[e0+e] - nbase;
      atomicAdd(&srow[erd[it]+1], 1);
    }
  }
  // h = x@W; pack adjacent-feature pairs via shfl (f parity == lane parity)
  for (int i = tid; i < NODES*16; i += NT) {
    int n = i >> 4, f = i & 15;
    const float* xp = x + (size_t)(nbase + n)*KIN;
    float xq = (f < KIN) ? xp[f] : 0.f;
    if (BNIN && f < KIN) xq = fmaf(xq, instats[f], instats[16+f]);
    float hv = 0.f;
#pragma unroll
    for (int j = 0; j < KIN; ++j) hv = fmaf(__shfl(xq, j, 16), sWl[j*16 + f], hv);
    unsigned int hb = (unsigned int)f2b(hv);
    unsigned int partner = (unsigned int)__shfl_xor((int)hb, 1);
    if ((f & 1) == 0) shp[n*9 + (f >> 1)] = hb | (partner << 16);
    float s1 = hv * sas[f], s2 = hv * sad[f];
#pragma unroll
    for (int m = 8; m >= 1; m >>= 1) { s1 += __shfl_xor(s1, m); s2 += __shfl_xor(s2, m); }
    if (f == 0) { sss[n] = s1; ssd[n] = s2; }
  }
  __syncthreads();

  constexpr int NC = 32, CS = (NODES + NC - 1) / NC;
  if (tid < NC) {
    int run = 0, lo = tid*CS, hi = (tid+1)*CS < NODES ? (tid+1)*CS : NODES;
    for (int i = lo; i < hi; ++i) { run += srow[i+1]; srow[i+1] = run; }
    schunk[tid] = run;
  }
  __syncthreads();
  if (tid == 0) { int base = 0; for (int c = 0; c < NC; ++c) { int t2 = schunk[c]; schunk[c] = base; base += t2; } }
  __syncthreads();
  for (int i = tid; i < NODES; i += NT) srow[i+1] += schunk[i/CS];
  __syncthreads();

#pragma unroll
  for (int it = 0; it < EIT; ++it) {
    if (erd[it] >= 0) {
      int slot = atomicAdd(&srow[erd[it]], 1);
      float l = sss[ers[it]] + ssd[erd[it]];
      l = fmaxf(l, 0.2f*l);
      float ex = __expf(l);
      spk[slot] = ((__float_as_uint(ex) + 0x8000u) & 0xffff0000u) | (unsigned int)ers[it];
    }
  }
  __syncthreads();

  {
    const int lane = tid & 7, grp = tid >> 3;   // NT/8 node groups
    for (int n = grp; n < NODES; n += (NT >> 3)) {
      float ls = sss[n] + ssd[n];
      ls = fmaxf(ls, 0.2f*ls);
      float exs = __expf(ls);
      unsigned int hp = shp[n*9 + lane];
      float aLo = exs * b2f((unsigned short)hp);
      float aHi = exs * b2f((unsigned short)(hp >> 16));
      float sum = exs;
      int j = (n > 0) ? srow[n-1] : 0, j1 = srow[n];
      for (; j + 4 <= j1; j += 4) {
        unsigned int p0 = spk[j], p1 = spk[j+1], p2 = spk[j+2], p3 = spk[j+3];
        float e0 = __uint_as_float(p0 & 0xffff0000u);
        float e1 = __uint_as_float(p1 & 0xffff0000u);
        float e2 = __uint_as_float(p2 & 0xffff0000u);
        float e3 = __uint_as_float(p3 & 0xffff0000u);
        unsigned int h0 = shp[(p0 & 0xffffu)*9 + lane];
        unsigned int h1 = shp[(p1 & 0xffffu)*9 + lane];
        unsigned int h2 = shp[(p2 & 0xffffu)*9 + lane];
        unsigned int h3 = shp[(p3 & 0xffffu)*9 + lane];
        aLo = fmaf(e0, b2f((unsigned short)h0), aLo);
        aHi = fmaf(e0, b2f((unsigned short)(h0 >> 16)), aHi); sum += e0;
        aLo = fmaf(e1, b2f((unsigned short)h1), aLo);
        aHi = fmaf(e1, b2f((unsigned short)(h1 >> 16)), aHi); sum += e1;
        aLo = fmaf(e2, b2f((unsigned short)h2), aLo);
        aHi = fmaf(e2, b2f((unsigned short)(h2 >> 16)), aHi); sum += e2;
        aLo = fmaf(e3, b2f((unsigned short)h3), aLo);
        aHi = fmaf(e3, b2f((unsigned short)(h3 >> 16)), aHi); sum += e3;
      }
      for (; j < j1; ++j) {
        unsigned int p0 = spk[j];
        float e0 = __uint_as_float(p0 & 0xffff0000u);
        unsigned int h0 = shp[(p0 & 0xffffu)*9 + lane];
        aLo = fmaf(e0, b2f((unsigned short)h0), aLo);
        aHi = fmaf(e0, b2f((unsigned short)(h0 >> 16)), aHi); sum += e0;
      }
      float inv = 1.f / sum;
      float vLo = fmaxf(fmaf(aLo, inv, sWl[KIN*16 + 2*lane]), 0.f);
      float vHi = fmaxf(fmaf(aHi, inv, sWl[KIN*16 + 2*lane + 1]), 0.f);
      int* pp = (int*)pooled + (size_t)cluster[nbase + n]*16 + 2*lane;
      atomicMax(pp,     __float_as_int(vLo));
      atomicMax(pp + 1, __float_as_int(vHi));
    }
  }
  __syncthreads();   // drains this block's atomics (vmcnt(0) before barrier)

  // BN partials over this block's exclusive pooled slice
  {
    float s = 0.f, q = 0.f;
    const float* po = pooled + (size_t)b*NPOOL*16;
    int f = tid & 15;
    for (int r = tid >> 4; r < NPOOL; r += (NT >> 4)) {
      float v = po[r*16 + f];
      s += v; q = fmaf(v, v, q);
    }
    float* red = (float*)shp;          // >= 2*NT floats
    red[tid] = s; red[NT + tid] = q;
    __syncthreads();
    for (int o = NT >> 1; o >= 16; o >>= 1) {
      if (tid < o) { red[tid] += red[tid + o]; red[NT + tid] += red[NT + tid + o]; }
      __syncthreads();
    }
    if (tid < 16) { bnp[b*32 + tid] = red[tid]; bnp[b*32 + 16 + tid] = red[NT + tid]; }
  }
}

// ===================== final GEMV =====================
__global__ __launch_bounds__(64)
void k_gemv_out(const float* __restrict__ parts, long pstrideA,
                const float* __restrict__ abias,
                const float* __restrict__ w,
                const float* __restrict__ b, float* __restrict__ out) {
  int r = blockIdx.x, l = threadIdx.x;
  float s = 0.f;
  for (int k = l; k < 384; k += 64) {
    const float* p = parts + (size_t)r*384 + k;
    float h = p[0] + p[pstrideA] + p[2*pstrideA] + p[3*pstrideA] + abias[k];
    h = h > 0.f ? h : expm1f(h);
    s = fmaf(h, w[k], s);
  }
#pragma unroll
  for (int o = 32; o > 0; o >>= 1) s += __shfl_down(s, o);
  if (l == 0) out[r] = s + b[0];
}

// ===================== host orchestration =====================
extern "C" void kernel_launch(void* const* d_in, const int* in_sizes, int n_in,
                              void* d_out, int out_size, void* d_ws, size_t ws_size,
                              hipStream_t stream) {
  (void)n_in; (void)out_size;
  const int B = 512;
  const int nd  = B*40;
  const int nc1 = B*512;
  const int nc2 = B*400;
  const int Ec0 = in_sizes[42]/2;
  const int Ec1 = in_sizes[43]/2;

  const float* drug_x = (const float*)d_in[0];
  const float* cell_x = (const float*)d_in[1];
  const float* gW1[3] = {(const float*)d_in[2],(const float*)d_in[8],(const float*)d_in[14]};
  const float* gb1[3] = {(const float*)d_in[3],(const float*)d_in[9],(const float*)d_in[15]};
  const float* gW2[3] = {(const float*)d_in[4],(const float*)d_in[10],(const float*)d_in[16]};
  const float* gb2[3] = {(const float*)d_in[5],(const float*)d_in[11],(const float*)d_in[17]};
  const float* gg [3] = {(const float*)d_in[6],(const float*)d_in[12],(const float*)d_in[18]};
  const float* gbe[3] = {(const float*)d_in[7],(const float*)d_in[13],(const float*)d_in[19]};
  const float* demb_W = (const float*)d_in[20]; const float* demb_b = (const float*)d_in[21];
  const float* gatW[2]  = {(const float*)d_in[22],(const float*)d_in[26]};
  const float* gatAS[2] = {(const float*)d_in[23],(const float*)d_in[27]};
  const float* gatAD[2] = {(const float*)d_in[24],(const float*)d_in[28]};
  const float* gatB[2]  = {(const float*)d_in[25],(const float*)d_in[29]};
  const float* cembW1 = (const float*)d_in[30]; const float* cembb1 = (const float*)d_in[31];
  const float* cembW2 = (const float*)d_in[32]; const float* cembb2 = (const float*)d_in[33];
  const float* regW1 = (const float*)d_in[34]; const float* regb1 = (const float*)d_in[35];
  const float* regW2 = (const float*)d_in[36]; const float* regb2 = (const float*)d_in[37];
  const float* regW3 = (const float*)d_in[38]; const float* regb3 = (const float*)d_in[39];
  const int* dei = (const int*)d_in[40];
  const int* ei0 = (const int*)d_in[42];
  const int* ei1 = (const int*)d_in[43];
  const int* cl0 = (const int*)d_in[44];
  const int* cl1 = (const int*)d_in[45];
  const int Ed  = in_sizes[40]/2;
  const int *dsrc = dei, *ddst = dei + Ed;
  const int *src0 = ei0, *dst0 = ei0 + Ec0;
  const int *src1 = ei1, *dst1 = ei1 + Ec1;
  float* out = (float*)d_out;

  // ---- workspace layout ----
  char* base = (char*)d_ws; size_t off = 0;
  auto AL = [&](size_t bytes)->char* { char* p = base + off; off = (off + bytes + 255) & ~(size_t)255; return p; };
  float* h_cat   = (float*)AL((size_t)512*384*4);
  float* xd      = (float*)AL((size_t)512*384*4);
  float* pooled1 = (float*)AL((size_t)nc1*16*4);
  float* pooled2 = (float*)AL((size_t)nc2*16*4);
  float* st_g0   = (float*)AL(256*4);
  float* st_g1   = (float*)AL(256*4);
  float* st_g2   = (float*)AL(256*4);
  float* st16_0  = (float*)AL(32*4);
  float* st16_1  = (float*)AL(32*4);
  float* bparts  = (float*)AL((size_t)512*256*4);
  unsigned short* Wt6 = (unsigned short*)AL((size_t)6*128*136*2);
  char*  S       = base + off;
  if (ws_size < off + (size_t)53*1024*1024) return;

  dim3 b256(256);

  // drug-phase scratch (S)
  float* pre0 = (float*)(S);
  float* pre1 = pre0 + (size_t)nd*128;
  float* pre2 = pre1 + (size_t)nd*128;
  unsigned short* xin_b = (unsigned short*)(pre2 + (size_t)nd*128);
  float* pre[3] = {pre0, pre1, pre2};
  float* stg[3] = {st_g0, st_g1, st_g2};

  // cell-phase scratch (S, reused after drug pool)
  size_t so = 0;
  auto SB = [&](size_t bytes)->char* { char* p = S + so; so = (so + bytes + 255) & ~(size_t)255; return p; };
  unsigned short* Abf = (unsigned short*)SB((size_t)512*6400*2);
  unsigned short* Btb = (unsigned short*)SB((size_t)1024*6400*2);
  float* parts1 = (float*)SB((size_t)8*512*1024*4);
  float* parts2 = (float*)SB((size_t)8*512*256*4);
  float* partsA = (float*)SB((size_t)4*512*384*4);
  float* partsB = (float*)SB((size_t)4*512*384*4);
  float* cembh = (float*)Abf;   // reduce dst (Abf dead post-mfma)

  // ================= DRUG BRANCH (bf16 MFMA GIN) =================
  k_w2bt6<<<dim3(68, 6), b256, 0, stream>>>(gW1[0], gW1[1], gW1[2],
                                            gW2[0], gW2[1], gW2[2], Wt6);
  for (int L = 0; L < 3; ++L) {
    if (L == 0)
      k_gin_agg_b<77,0><<<dim3(512), b256, 0, stream>>>(drug_x, nullptr, dsrc, ddst, xin_b);
    else
      k_gin_agg_b<128,1><<<dim3(512), b256, 0, stream>>>(pre[L-1], stg[L-1], dsrc, ddst, xin_b);
    k_gin_fmfma<<<dim3(160), dim3(512), 0, stream>>>(
        xin_b, Wt6 + (size_t)L*128*136, Wt6 + (size_t)(3+L)*128*136,
        gb1[L], gb2[L], pre[L], bparts);
    k_bn_fin<<<dim3(1), dim3(128), 0, stream>>>(bparts, 160, 128, 1.f/nd, gg[L], gbe[L], stg[L]);
  }
  k_drug_pool_bn<<<dim3(512), dim3(128), 0, stream>>>(pre0, pre1, pre2, st_g0, st_g1, st_g2, xd);
  k_gemm<1,0,0,0,0,0><<<dim3(2,8,1), b256, 0, stream>>>(
      xd, 384, demb_W, 128, demb_b, h_cat, 384, 384, 0, 0, nullptr, nullptr, nullptr);

  // cembW1 -> bf16 transposed (drug scratch dead now)
  k_w2bt<<<dim3(200, 32), b256, 0, stream>>>(cembW1, Btb);

  // ================= CELL BRANCH: two fused GAT layers (BN partials in-kernel) =====
  k_gat_lds<706,512,3,8000,0,0,1024><<<dim3(512), dim3(1024), 0, stream>>>(
      cell_x, src0, dst0, Ec0/512, gatW[0], gatAS[0], gatAD[0], gatB[0], cl0,
      nullptr, pooled1, bparts);
  k_bn_fin<<<dim3(1), dim3(16), 0, stream>>>(bparts, 512, 16, 1.f/nc1, nullptr, nullptr, st16_0);

  k_gat_lds<512,400,16,8000,1,1,1024><<<dim3(512), dim3(1024), 0, stream>>>(
      pooled1, src1, dst1, Ec1, gatW[1], gatAS[1], gatAD[1], gatB[1], cl1,
      st16_0, pooled2, bparts);
  k_bn_fin<<<dim3(1), dim3(16), 0, stream>>>(bparts, 512, 16, 1.f/nc2, nullptr, nullptr, st16_1);

  // ================= cell embedding MLP =================
  k_a2bn<<<dim3(3200), b256, 0, stream>>>(pooled2, st16_1, Abf, 512*6400/4);
  k_mfma128<<<dim3(8, 4, 8), b256, 0, stream>>>(
      Abf, Btb, parts1, 1024, 6400, 800, (long)512*1024);
  k_reduce<1><<<dim3((512*1024+255)/256), b256, 0, stream>>>(
      parts1, 8, (long)512*1024, cembb1, cembh, 1024, 512, 1024);
  k_gemm<0,1,0,0,0,0><<<dim3(4,8,8), b256, 0, stream>>>(
      cembh, 1024, cembW2, 256, nullptr, parts2, 256, 128,
      (long)512*256, 0, nullptr, nullptr, nullptr);
  k_reduce<1><<<dim3((512*256+255)/256), b256, 0, stream>>>(
      parts2, 8, (long)512*256, cembb2, h_cat + 128, 384, 512, 256);

  // ================= regressor =================
  k_gemm<0,1,0,0,0,0><<<dim3(6,8,4), b256, 0, stream>>>(
      h_cat, 384, regW1, 384, nullptr, partsA, 384, 96,
      (long)512*384, 0, nullptr, nullptr, nullptr);
  k_gemm<0,1,0,4,2,0><<<dim3(6,8,4), b256, 0, stream>>>(
      partsA, 384, regW2, 384, nullptr, partsB, 384, 96,
      (long)512*384, (long)512*384, regb1, nullptr, nullptr);
  k_gemv_out<<<dim3(512), dim3(64), 0, stream>>>(
      partsB, (long)512*384, regb2, regW3, regb3, out);
}

// Round 22
// 399.855 us; speedup vs baseline: 1.0981x; 1.0739x over previous
//
#include <hip/hip_runtime.h>
#include <math.h>

typedef __attribute__((ext_vector_type(8))) short bfrag;
typedef __attribute__((ext_vector_type(4))) float ffrag;

__device__ __forceinline__ unsigned short f2b(float v) {
  return (unsigned short)((__float_as_uint(v) + 0x8000u) >> 16);
}
__device__ __forceinline__ float b2f(unsigned short u) {
  return __uint_as_float((unsigned int)u << 16);
}

// ===================== batched weight transpose -> bf16 [128][136] =====================
__global__ __launch_bounds__(256)
void k_w2bt6(const float* __restrict__ w0, const float* __restrict__ w1,
             const float* __restrict__ w2, const float* __restrict__ w3,
             const float* __restrict__ w4, const float* __restrict__ w5,
             unsigned short* __restrict__ out) {
  int t = blockIdx.x*256 + threadIdx.x;
  if (t >= 128*136) return;
  int L = blockIdx.y;
  const float* W; int Ksrc = 128;
  switch (L) {
    case 0: W = w0; Ksrc = 77; break;
    case 1: W = w1; break;
    case 2: W = w2; break;
    case 3: W = w3; break;
    case 4: W = w4; break;
    default: W = w5; break;
  }
  int n = t / 136, k = t - n*136;
  float v = (k < Ksrc) ? W[(size_t)k*128 + n] : 0.f;
  out[(size_t)L*128*136 + t] = f2b(v);
}

// ===================== per-batch GIN aggregation -> bf16 (in-LDS CSR) =====================
template<int KIN, int BNIN>
__global__ __launch_bounds__(256)
void k_gin_agg_b(const float* __restrict__ xg, const float* __restrict__ st,
                 const int* __restrict__ esrc, const int* __restrict__ edst,
                 unsigned short* __restrict__ xin) {
  __shared__ float xb[40*128];
  __shared__ unsigned short scsr[160];
  __shared__ int srow[41];
  const int b = blockIdx.x, tid = threadIdx.x, nbase = b*40;
  if (tid <= 40) srow[tid] = 0;
  __syncthreads();
  int rs = -1, rd = -1;
  if (tid < 160) {
    rs = esrc[b*160+tid] - nbase;
    rd = edst[b*160+tid] - nbase;
    atomicAdd(&srow[rd+1], 1);
  }
  for (int i = tid; i < 40*KIN; i += 256) {
    int n = i/KIN, f = i - n*KIN;
    float v = xg[(size_t)(nbase+n)*KIN + f];
    if (BNIN) v = fmaf(v, st[f], st[KIN+f]);
    xb[n*128 + f] = v;
  }
  __syncthreads();
  if (tid == 0) { int run = 0; for (int i = 1; i <= 40; ++i) { run += srow[i]; srow[i] = run; } }
  __syncthreads();
  if (tid < 160) { int slot = atomicAdd(&srow[rd], 1); scsr[slot] = (unsigned short)rs; }
  __syncthreads();
  for (int i = tid; i < 40*128; i += 256) {
    int n = i >> 7, f = i & 127;
    float a = 0.f;
    if (f < KIN) {
      a = xb[n*128 + f];
      int j0 = n ? srow[n-1] : 0, j1 = srow[n];
      for (int j = j0; j < j1; ++j) a += xb[scsr[j]*128 + f];
    }
    xin[(size_t)nbase*128 + i] = f2b(a);
  }
}

// ===================== fused GIN layer via MFMA =====================
// 64-row blocks (grid 320 -> all 256 CUs busy, was 160). Only the A-tile is
// LDS-staged (17KB, 7 blocks/CU); W fragments read directly from global Wt6 —
// per-block W reuse lands in L2 (~82MB @35TB/s chip-wide), and lanes
// 0/16/32/48 read consecutive 16B of one row => full 64B segments.
__global__ __launch_bounds__(256)
void k_gin_fmfma(const unsigned short* __restrict__ Ax,
                 const unsigned short* __restrict__ W1t,
                 const unsigned short* __restrict__ W2t,
                 const float* __restrict__ b1, const float* __restrict__ b2,
                 float* __restrict__ outp, float* __restrict__ bnp) {
  __shared__ unsigned short Ab[64*136];
  __shared__ float cred[4*128], cred2[4*128];
  const int tid = threadIdx.x;
  const int row0 = blockIdx.x << 6;
  for (int i = tid; i < 64*17; i += 256) {
    int r = i / 17, c8 = (i - r*17) << 3;
    uint4 v = make_uint4(0,0,0,0);
    if (c8 < 128) v = *(const uint4*)(Ax + (size_t)(row0 + r)*128 + c8);
    *(uint4*)&Ab[r*136 + c8] = v;
  }
  __syncthreads();
  const int wave = tid >> 6, lane = tid & 63;
  const int fr = lane & 15, fk = (lane >> 4) << 3;
  const int wrow = wave << 4;
  const int mrow = (lane >> 4) << 2;
  float b1v[8], b2v[8];
#pragma unroll
  for (int n = 0; n < 8; ++n) { b1v[n] = b1[(n<<4) + fr]; b2v[n] = b2[(n<<4) + fr]; }

  ffrag acc[8];
#pragma unroll
  for (int n = 0; n < 8; ++n) acc[n] = (ffrag){0.f,0.f,0.f,0.f};
#pragma unroll
  for (int s = 0; s < 4; ++s) {
    bfrag af = *(const bfrag*)&Ab[(wrow + fr)*136 + (s<<5) + fk];
#pragma unroll
    for (int n = 0; n < 8; ++n) {
      bfrag bf = *(const bfrag*)&W1t[((n<<4) + fr)*136 + (s<<5) + fk];
      acc[n] = __builtin_amdgcn_mfma_f32_16x16x32_bf16(af, bf, acc[n], 0, 0, 0);
    }
  }
#pragma unroll
  for (int n = 0; n < 8; ++n)
#pragma unroll
    for (int r = 0; r < 4; ++r) {
      float v = fmaxf(acc[n][r] + b1v[n], 0.f);
      Ab[(wrow + mrow + r)*136 + (n<<4) + fr] = f2b(v);
    }
  __syncthreads();

  ffrag acc2[8];
#pragma unroll
  for (int n = 0; n < 8; ++n) acc2[n] = (ffrag){0.f,0.f,0.f,0.f};
#pragma unroll
  for (int s = 0; s < 4; ++s) {
    bfrag af = *(const bfrag*)&Ab[(wrow + fr)*136 + (s<<5) + fk];
#pragma unroll
    for (int n = 0; n < 8; ++n) {
      bfrag bf = *(const bfrag*)&W2t[((n<<4) + fr)*136 + (s<<5) + fk];
      acc2[n] = __builtin_amdgcn_mfma_f32_16x16x32_bf16(af, bf, acc2[n], 0, 0, 0);
    }
  }
#pragma unroll
  for (int n = 0; n < 8; ++n) {
    float s = 0.f, q = 0.f;
#pragma unroll
    for (int r = 0; r < 4; ++r) {
      float v = fmaxf(acc2[n][r] + b2v[n], 0.f);
      outp[(size_t)(row0 + wrow + mrow + r)*128 + (n<<4) + fr] = v;
      s += v; q = fmaf(v, v, q);
    }
    s += __shfl_xor(s, 16); s += __shfl_xor(s, 32);
    q += __shfl_xor(q, 16); q += __shfl_xor(q, 32);
    if (lane < 16) { cred[wave*128 + (n<<4) + fr] = s; cred2[wave*128 + (n<<4) + fr] = q; }
  }
  __syncthreads();
  if (tid < 128) {
    float S = 0.f, Q = 0.f;
#pragma unroll
    for (int w = 0; w < 4; ++w) { S += cred[w*128 + tid]; Q += cred2[w*128 + tid]; }
    bnp[blockIdx.x*256 + tid] = S;
    bnp[blockIdx.x*256 + 128 + tid] = Q;
  }
}

// xd[b, L*128+f] = max_n affineBN(pre_L[b*40+n, f])
__global__ __launch_bounds__(128)
void k_drug_pool_bn(const float* __restrict__ p0, const float* __restrict__ p1,
                    const float* __restrict__ p2,
                    const float* __restrict__ s0, const float* __restrict__ s1,
                    const float* __restrict__ s2,
                    float* __restrict__ xd) {
  int b = blockIdx.x, f = threadIdx.x;
  const float* ps[3] = {p0,p1,p2};
  const float* ss[3] = {s0,s1,s2};
#pragma unroll
  for (int L = 0; L < 3; ++L) {
    float sc = ss[L][f], sh = ss[L][128+f];
    float m = -3.0e38f;
    const float* p = ps[L] + (size_t)b*40*128 + f;
    for (int n = 0; n < 40; ++n) m = fmaxf(m, fmaf(p[n*128], sc, sh));
    xd[(size_t)b*384 + L*128 + f] = m;
  }
}

// ===================== GEMM (f32, 64x64 tile) =====================
template<int ACT, int PART, int BNA, int NPA, int ACTA, int BNP>
__global__ __launch_bounds__(256)
void k_gemm(const float* __restrict__ A, int lda,
            const float* __restrict__ B, int ldb,
            const float* __restrict__ bias,
            float* __restrict__ C, int ldc, int Kchunk,
            long pstrideC, long pstrideA,
            const float* __restrict__ abias,
            const float* __restrict__ bnst,
            float* __restrict__ bnp) {
  __shared__ __align__(16) float As[32][68];
  __shared__ __align__(16) float Bs[32][68];
  const int tid = threadIdx.x;
  const int tx = tid & 15, ty = tid >> 4;
  const int row0 = blockIdx.y << 6, col0 = blockIdx.x << 6;
  const int kb = blockIdx.z * Kchunk;
  if (PART) C += (size_t)blockIdx.z * pstrideC;
  float acc[4][4] = {{0.f}};
  for (int k0 = 0; k0 < Kchunk; k0 += 32) {
#pragma unroll
    for (int i = 0; i < 2; ++i) {
      int idx = tid + (i << 8);
      int r = idx >> 3, c = (idx & 7) << 2;
      const float* ap = A + (size_t)(row0 + r)*lda + (kb + k0 + c);
      float4 v = *(const float4*)ap;
      if (NPA > 1) {
#pragma unroll
        for (int z = 1; z < NPA; ++z) {
          float4 p = *(const float4*)(ap + (size_t)z*pstrideA);
          v.x += p.x; v.y += p.y; v.z += p.z; v.w += p.w;
        }
        const float* ab = abias + (kb + k0 + c);
        v.x += ab[0]; v.y += ab[1]; v.z += ab[2]; v.w += ab[3];
        if (ACTA == 1) {
          v.x=fmaxf(v.x,0.f); v.y=fmaxf(v.y,0.f); v.z=fmaxf(v.z,0.f); v.w=fmaxf(v.w,0.f);
        } else if (ACTA == 2) {
          v.x = v.x>0.f?v.x:expm1f(v.x); v.y = v.y>0.f?v.y:expm1f(v.y);
          v.z = v.z>0.f?v.z:expm1f(v.z); v.w = v.w>0.f?v.w:expm1f(v.w);
        }
      }
      if (BNA) {
        int fb = (kb + k0 + c) & 15;
        float4 sc = *(const float4*)&bnst[fb];
        float4 sh = *(const float4*)&bnst[16 + fb];
        v.x = fmaf(v.x, sc.x, sh.x); v.y = fmaf(v.y, sc.y, sh.y);
        v.z = fmaf(v.z, sc.z, sh.z); v.w = fmaf(v.w, sc.w, sh.w);
      }
      int sw = ((c >> 2) & 7) << 2;
      int rs = r ^ sw;
      As[c+0][rs]=v.x; As[c+1][rs]=v.y; As[c+2][rs]=v.z; As[c+3][rs]=v.w;
    }
#pragma unroll
    for (int i = 0; i < 2; ++i) {
      int idx = tid + (i << 8);
      int r = idx >> 4, c = (idx & 15) << 2;
      *(float4*)&Bs[r][c] = *(const float4*)(B + (size_t)(kb + k0 + r)*ldb + (col0 + c));
    }
    __syncthreads();
#pragma unroll
    for (int kk = 0; kk < 32; ++kk) {
      int sw = ((kk >> 2) & 7) << 2;
      float4 av = *(const float4*)&As[kk][(ty << 2) ^ sw];
      float4 bv = *(const float4*)&Bs[kk][tx << 2];
      acc[0][0]=fmaf(av.x,bv.x,acc[0][0]); acc[0][1]=fmaf(av.x,bv.y,acc[0][1]);
      acc[0][2]=fmaf(av.x,bv.z,acc[0][2]); acc[0][3]=fmaf(av.x,bv.w,acc[0][3]);
      acc[1][0]=fmaf(av.y,bv.x,acc[1][0]); acc[1][1]=fmaf(av.y,bv.y,acc[1][1]);
      acc[1][2]=fmaf(av.y,bv.z,acc[1][2]); acc[1][3]=fmaf(av.y,bv.w,acc[1][3]);
      acc[2][0]=fmaf(av.z,bv.x,acc[2][0]); acc[2][1]=fmaf(av.z,bv.y,acc[2][1]);
      acc[2][2]=fmaf(av.z,bv.z,acc[2][2]); acc[2][3]=fmaf(av.z,bv.w,acc[2][3]);
      acc[3][0]=fmaf(av.w,bv.x,acc[3][0]); acc[3][1]=fmaf(av.w,bv.y,acc[3][1]);
      acc[3][2]=fmaf(av.w,bv.z,acc[3][2]); acc[3][3]=fmaf(av.w,bv.w,acc[3][3]);
    }
    __syncthreads();
  }
#pragma unroll
  for (int i = 0; i < 4; ++i) {
    int r = row0 + (ty<<2) + i, c = col0 + (tx<<2);
    float4 v = make_float4(acc[i][0], acc[i][1], acc[i][2], acc[i][3]);
    if (!PART) {
      if (bias) { v.x += bias[c]; v.y += bias[c+1]; v.z += bias[c+2]; v.w += bias[c+3]; }
      if (ACT == 1) { v.x=fmaxf(v.x,0.f); v.y=fmaxf(v.y,0.f); v.z=fmaxf(v.z,0.f); v.w=fmaxf(v.w,0.f); }
      else if (ACT == 2) {
        v.x = v.x>0.f?v.x:expm1f(v.x); v.y = v.y>0.f?v.y:expm1f(v.y);
        v.z = v.z>0.f?v.z:expm1f(v.z); v.w = v.w>0.f?v.w:expm1f(v.w);
      }
    }
    *(float4*)(C + (size_t)r*ldc + c) = v;
  }
}

template<int ACT>
__global__ void k_reduce(const float* __restrict__ parts, int np, long pstride,
                         const float* __restrict__ bias,
                         float* __restrict__ out, int ldo, int M, int N) {
  int t = blockIdx.x*blockDim.x + threadIdx.x;
  if (t >= M*N) return;
  int r = t / N, c = t - r*N;
  float s = 0.f;
  for (int z = 0; z < np; ++z) s += parts[(size_t)z*pstride + t];
  s += bias[c];
  if (ACT == 1) s = fmaxf(s, 0.f);
  else if (ACT == 2) s = s > 0.f ? s : expm1f(s);
  out[(size_t)r*ldo + c] = s;
}

// ===================== bf16 conversion kernels (cemb1 MFMA path) =====================
__global__ __launch_bounds__(256)
void k_w2bt(const float* __restrict__ W, unsigned short* __restrict__ Bt) {
  __shared__ float tile[32][33];
  int bk = blockIdx.x << 5, bn = blockIdx.y << 5;
  int c = threadIdx.x & 31, r8 = threadIdx.x >> 5;
#pragma unroll
  for (int i = 0; i < 4; ++i) {
    int r = r8 + (i << 3);
    tile[r][c] = W[(size_t)(bk + r)*1024 + bn + c];
  }
  __syncthreads();
#pragma unroll
  for (int i = 0; i < 4; ++i) {
    int r = r8 + (i << 3);
    Bt[(size_t)(bn + r)*6400 + bk + c] = f2b(tile[c][r]);
  }
}

__global__ void k_a2bn(const float* __restrict__ x, const float* __restrict__ st,
                       unsigned short* __restrict__ o, int total4) {
  int t = blockIdx.x*blockDim.x + threadIdx.x;
  if (t >= total4) return;
  int fb = (t << 2) & 15;
  float4 v = *(const float4*)(x + ((size_t)t << 2));
  float4 sc = *(const float4*)&st[fb];
  float4 sh = *(const float4*)&st[16 + fb];
  ushort4 r;
  r.x = f2b(fmaf(v.x, sc.x, sh.x));
  r.y = f2b(fmaf(v.y, sc.y, sh.y));
  r.z = f2b(fmaf(v.z, sc.z, sh.z));
  r.w = f2b(fmaf(v.w, sc.w, sh.w));
  *(ushort4*)(o + ((size_t)t << 2)) = r;
}

// ===================== MFMA bf16 GEMM: 128x128 tile, split-K partials =====================
__global__ __launch_bounds__(256)
void k_mfma128(const unsigned short* __restrict__ A,
               const unsigned short* __restrict__ Bt,
               float* __restrict__ C, int ldc, int K,
               int Kchunk, long pstrideC) {
  __shared__ unsigned short Al[2][128*40];
  __shared__ unsigned short Bl[2][128*40];
  const int tid = threadIdx.x;
  const int row0 = blockIdx.y << 7, col0 = blockIdx.x << 7;
  const int kb = blockIdx.z * Kchunk;
  C += (size_t)blockIdx.z * pstrideC;
  const int wave = tid >> 6, lane = tid & 63;
  const int wr = wave >> 1, wc = wave & 1;
  const int fr = lane & 15, fk = (lane >> 4) << 3;
  const int lr = tid >> 1, lco = (tid & 1) << 4;

  ffrag acc[4][4];
#pragma unroll
  for (int i = 0; i < 4; ++i)
#pragma unroll
    for (int n = 0; n < 4; ++n) acc[i][n] = (ffrag){0.f, 0.f, 0.f, 0.f};

  const unsigned short* ag = A  + (size_t)(row0 + lr)*K + kb + lco;
  const unsigned short* bg = Bt + (size_t)(col0 + lr)*K + kb + lco;

  uint4 ra0 = *(const uint4*)ag, ra1 = *(const uint4*)(ag + 8);
  uint4 rb0 = *(const uint4*)bg, rb1 = *(const uint4*)(bg + 8);
  *(uint4*)&Al[0][lr*40 + lco] = ra0; *(uint4*)&Al[0][lr*40 + lco + 8] = ra1;
  *(uint4*)&Bl[0][lr*40 + lco] = rb0; *(uint4*)&Bl[0][lr*40 + lco + 8] = rb1;
  __syncthreads();

  const int NS = Kchunk >> 5;
  int cur = 0;
  for (int s = 0; s < NS; ++s) {
    if (s + 1 < NS) {
      const unsigned short* an = ag + ((s + 1) << 5);
      const unsigned short* bn = bg + ((s + 1) << 5);
      ra0 = *(const uint4*)an; ra1 = *(const uint4*)(an + 8);
      rb0 = *(const uint4*)bn; rb1 = *(const uint4*)(bn + 8);
    }
    bfrag af[4], bf[4];
#pragma unroll
    for (int i = 0; i < 4; ++i) af[i] = *(const bfrag*)&Al[cur][(wr*64 + i*16 + fr)*40 + fk];
#pragma unroll
    for (int n = 0; n < 4; ++n) bf[n] = *(const bfrag*)&Bl[cur][(wc*64 + n*16 + fr)*40 + fk];
#pragma unroll
    for (int i = 0; i < 4; ++i)
#pragma unroll
      for (int n = 0; n < 4; ++n)
        acc[i][n] = __builtin_amdgcn_mfma_f32_16x16x32_bf16(af[i], bf[n], acc[i][n], 0, 0, 0);
    if (s + 1 < NS) {
      cur ^= 1;
      *(uint4*)&Al[cur][lr*40 + lco] = ra0; *(uint4*)&Al[cur][lr*40 + lco + 8] = ra1;
      *(uint4*)&Bl[cur][lr*40 + lco] = rb0; *(uint4*)&Bl[cur][lr*40 + lco + 8] = rb1;
      __syncthreads();
    }
  }
  const int frow = (lane >> 4) << 2;
#pragma unroll
  for (int i = 0; i < 4; ++i)
#pragma unroll
    for (int n = 0; n < 4; ++n) {
      float* cp = C + (size_t)(row0 + wr*64 + i*16 + frow)*ldc + col0 + wc*64 + n*16 + fr;
#pragma unroll
      for (int r = 0; r < 4; ++r) cp[(size_t)r*ldc] = acc[i][n][r];
    }
}

// ===================== BN finalize: parallel (512 thr) partials -> affine =====================
__global__ __launch_bounds__(512)
void k_bn_fin(const float* __restrict__ parts, int nb, int C, float invn,
              const float* __restrict__ g, const float* __restrict__ be,
              float* __restrict__ stats) {
  __shared__ float rs[512], rq[512];
  const int tid = threadIdx.x;
  const int f = tid % C;
  const int chunks = 512 / C;
  const int c = tid / C;
  float s = 0.f, q = 0.f;
  for (int z = c; z < nb; z += chunks) {
    s += parts[(size_t)z*2*C + f];
    q += parts[(size_t)z*2*C + C + f];
  }
  rs[tid] = s; rq[tid] = q;
  __syncthreads();
  for (int o = 256; o >= C; o >>= 1) {
    if (tid < o) { rs[tid] += rs[tid + o]; rq[tid] += rq[tid + o]; }
    __syncthreads();
  }
  if (tid < C) {
    float mu = rs[tid]*invn;
    float var = fmaxf(rq[tid]*invn - mu*mu, 0.f);
    float rstd = rsqrtf(var + 1e-5f);
    float sc = g ? g[tid]*rstd : rstd;
    stats[tid] = sc;
    stats[C+tid] = (be ? be[tid] : 0.f) - mu*sc;
  }
}

// ===================== fused per-batch GAT layer (round-16 best config) =====================
template<int NODES, int NPOOL, int KIN, int MAXE, int SORTED, int BNIN, int NT>
__global__ __launch_bounds__(NT, 8)
void k_gat_lds(const float* __restrict__ x,
               const int* __restrict__ esrc, const int* __restrict__ edst, int Earg,
               const float* __restrict__ W, const float* __restrict__ as_,
               const float* __restrict__ ad_, const float* __restrict__ bias,
               const int* __restrict__ cluster,
               const float* __restrict__ instats,
               float* __restrict__ pooled, float* __restrict__ bnp) {
  constexpr int EIT = (MAXE + NT - 1) / NT;
  __shared__ unsigned int shp[NODES*9];   // h as packed bf16 pairs, stride 9
  __shared__ unsigned int spk[MAXE];
  __shared__ float sss[NODES], ssd[NODES];
  __shared__ int srow[NODES+1];
  __shared__ float sWl[KIN*16 + 16];
  __shared__ float sas[16], sad[16];
  __shared__ int schunk[32];
  __shared__ int sr2[2];
  const int b = blockIdx.x;
  const int tid = threadIdx.x;
  const int nbase = b*NODES;

  if (tid < KIN*16) sWl[tid] = W[tid];
  if (tid >= 64 && tid < 80)  sWl[KIN*16 + tid-64] = bias[tid-64];
  if (tid >= 80 && tid < 96)  sas[tid-80] = as_[tid-80];
  if (tid >= 96 && tid < 112) sad[tid-96] = ad_[tid-96];
  if (SORTED && tid == 0) {
    int a = 0, c = Earg;
    while (a < c) { int m = (a+c) >> 1; if (esrc[m] < nbase) a = m+1; else c = m; }
    sr2[0] = a;
    c = Earg;
    int nend = nbase + NODES;
    while (a < c) { int m = (a+c) >> 1; if (esrc[m] < nend) a = m+1; else c = m; }
    sr2[1] = a;
  }
  for (int i = tid; i <= NODES; i += NT) srow[i] = 0;
  __syncthreads();

  int e0, Eblk;
  if (SORTED) { e0 = sr2[0]; Eblk = sr2[1] - sr2[0]; }
  else        { e0 = b*Earg; Eblk = Earg; }

  int ers[EIT], erd[EIT];
#pragma unroll
  for (int it = 0; it < EIT; ++it) {
    int e = tid + it*NT;
    ers[it] = -1; erd[it] = -1;
    if (e < Eblk) {
      ers[it] = esrc[e0+e] - nbase;
      erd[it] = edst[e0+e] - nbase;
      atomicAdd(&srow[erd[it]+1], 1);
    }
  }
  // h = x@W; pack adjacent-feature pairs via shfl (f parity == lane parity)
  for (int i = tid; i < NODES*16; i += NT) {
    int n = i >> 4, f = i & 15;
    const float* xp = x + (size_t)(nbase + n)*KIN;
    float xq = (f < KIN) ? xp[f] : 0.f;
    if (BNIN && f < KIN) xq = fmaf(xq, instats[f], instats[16+f]);
    float hv = 0.f;
#pragma unroll
    for (int j = 0; j < KIN; ++j) hv = fmaf(__shfl(xq, j, 16), sWl[j*16 + f], hv);
    unsigned int hb = (unsigned int)f2b(hv);
    unsigned int partner = (unsigned int)__shfl_xor((int)hb, 1);
    if ((f & 1) == 0) shp[n*9 + (f >> 1)] = hb | (partner << 16);
    float s1 = hv * sas[f], s2 = hv * sad[f];
#pragma unroll
    for (int m = 8; m >= 1; m >>= 1) { s1 += __shfl_xor(s1, m); s2 += __shfl_xor(s2, m); }
    if (f == 0) { sss[n] = s1; ssd[n] = s2; }
  }
  __syncthreads();

  constexpr int NC = 32, CS = (NODES + NC - 1) / NC;
  if (tid < NC) {
    int run = 0, lo = tid*CS, hi = (tid+1)*CS < NODES ? (tid+1)*CS : NODES;
    for (int i = lo; i < hi; ++i) { run += srow[i+1]; srow[i+1] = run; }
    schunk[tid] = run;
  }
  __syncthreads();
  if (tid == 0) { int base = 0; for (int c = 0; c < NC; ++c) { int t2 = schunk[c]; schunk[c] = base; base += t2; } }
  __syncthreads();
  for (int i = tid; i < NODES; i += NT) srow[i+1] += schunk[i/CS];
  __syncthreads();

#pragma unroll
  for (int it = 0; it < EIT; ++it) {
    if (erd[it] >= 0) {
      int slot = atomicAdd(&srow[erd[it]], 1);
      float l = sss[ers[it]] + ssd[erd[it]];
      l = fmaxf(l, 0.2f*l);
      float ex = __expf(l);
      spk[slot] = ((__float_as_uint(ex) + 0x8000u) & 0xffff0000u) | (unsigned int)ers[it];
    }
  }
  __syncthreads();

  {
    const int lane = tid & 7, grp = tid >> 3;   // NT/8 node groups
    for (int n = grp; n < NODES; n += (NT >> 3)) {
      float ls = sss[n] + ssd[n];
      ls = fmaxf(ls, 0.2f*ls);
      float exs = __expf(ls);
      unsigned int hp = shp[n*9 + lane];
      float aLo = exs * b2f((unsigned short)hp);
      float aHi = exs * b2f((unsigned short)(hp >> 16));
      float sum = exs;
      int j = (n > 0) ? srow[n-1] : 0, j1 = srow[n];
      for (; j + 4 <= j1; j += 4) {
        unsigned int p0 = spk[j], p1 = spk[j+1], p2 = spk[j+2], p3 = spk[j+3];
        float e0 = __uint_as_float(p0 & 0xffff0000u);
        float e1 = __uint_as_float(p1 & 0xffff0000u);
        float e2 = __uint_as_float(p2 & 0xffff0000u);
        float e3 = __uint_as_float(p3 & 0xffff0000u);
        unsigned int h0 = shp[(p0 & 0xffffu)*9 + lane];
        unsigned int h1 = shp[(p1 & 0xffffu)*9 + lane];
        unsigned int h2 = shp[(p2 & 0xffffu)*9 + lane];
        unsigned int h3 = shp[(p3 & 0xffffu)*9 + lane];
        aLo = fmaf(e0, b2f((unsigned short)h0), aLo);
        aHi = fmaf(e0, b2f((unsigned short)(h0 >> 16)), aHi); sum += e0;
        aLo = fmaf(e1, b2f((unsigned short)h1), aLo);
        aHi = fmaf(e1, b2f((unsigned short)(h1 >> 16)), aHi); sum += e1;
        aLo = fmaf(e2, b2f((unsigned short)h2), aLo);
        aHi = fmaf(e2, b2f((unsigned short)(h2 >> 16)), aHi); sum += e2;
        aLo = fmaf(e3, b2f((unsigned short)h3), aLo);
        aHi = fmaf(e3, b2f((unsigned short)(h3 >> 16)), aHi); sum += e3;
      }
      for (; j < j1; ++j) {
        unsigned int p0 = spk[j];
        float e0 = __uint_as_float(p0 & 0xffff0000u);
        unsigned int h0 = shp[(p0 & 0xffffu)*9 + lane];
        aLo = fmaf(e0, b2f((unsigned short)h0), aLo);
        aHi = fmaf(e0, b2f((unsigned short)(h0 >> 16)), aHi); sum += e0;
      }
      float inv = 1.f / sum;
      float vLo = fmaxf(fmaf(aLo, inv, sWl[KIN*16 + 2*lane]), 0.f);
      float vHi = fmaxf(fmaf(aHi, inv, sWl[KIN*16 + 2*lane + 1]), 0.f);
      int* pp = (int*)pooled + (size_t)cluster[nbase + n]*16 + 2*lane;
      atomicMax(pp,     __float_as_int(vLo));
      atomicMax(pp + 1, __float_as_int(vHi));
    }
  }
  __syncthreads();   // drains this block's atomics (vmcnt(0) before barrier)

  // BN partials over this block's exclusive pooled slice
  {
    float s = 0.f, q = 0.f;
    const float* po = pooled + (size_t)b*NPOOL*16;
    int f = tid & 15;
    for (int r = tid >> 4; r < NPOOL; r += (NT >> 4)) {
      float v = po[r*16 + f];
      s += v; q = fmaf(v, v, q);
    }
    float* red = (float*)shp;          // >= 2*NT floats
    red[tid] = s; red[NT + tid] = q;
    __syncthreads();
    for (int o = NT >> 1; o >= 16; o >>= 1) {
      if (tid < o) { red[tid] += red[tid + o]; red[NT + tid] += red[NT + tid + o]; }
      __syncthreads();
    }
    if (tid < 16) { bnp[b*32 + tid] = red[tid]; bnp[b*32 + 16 + tid] = red[NT + tid]; }
  }
}

// ===================== final GEMV =====================
__global__ __launch_bounds__(64)
void k_gemv_out(const float* __restrict__ parts, long pstrideA,
                const float* __restrict__ abias,
                const float* __restrict__ w,
                const float* __restrict__ b, float* __restrict__ out) {
  int r = blockIdx.x, l = threadIdx.x;
  float s = 0.f;
  for (int k = l; k < 384; k += 64) {
    const float* p = parts + (size_t)r*384 + k;
    float h = p[0] + p[pstrideA] + p[2*pstrideA] + p[3*pstrideA] + abias[k];
    h = h > 0.f ? h : expm1f(h);
    s = fmaf(h, w[k], s);
  }
#pragma unroll
  for (int o = 32; o > 0; o >>= 1) s += __shfl_down(s, o);
  if (l == 0) out[r] = s + b[0];
}

// ===================== host orchestration =====================
extern "C" void kernel_launch(void* const* d_in, const int* in_sizes, int n_in,
                              void* d_out, int out_size, void* d_ws, size_t ws_size,
                              hipStream_t stream) {
  (void)n_in; (void)out_size;
  const int B = 512;
  const int nd  = B*40;
  const int nc1 = B*512;
  const int nc2 = B*400;
  const int Ec0 = in_sizes[42]/2;
  const int Ec1 = in_sizes[43]/2;

  const float* drug_x = (const float*)d_in[0];
  const float* cell_x = (const float*)d_in[1];
  const float* gW1[3] = {(const float*)d_in[2],(const float*)d_in[8],(const float*)d_in[14]};
  const float* gb1[3] = {(const float*)d_in[3],(const float*)d_in[9],(const float*)d_in[15]};
  const float* gW2[3] = {(const float*)d_in[4],(const float*)d_in[10],(const float*)d_in[16]};
  const float* gb2[3] = {(const float*)d_in[5],(const float*)d_in[11],(const float*)d_in[17]};
  const float* gg [3] = {(const float*)d_in[6],(const float*)d_in[12],(const float*)d_in[18]};
  const float* gbe[3] = {(const float*)d_in[7],(const float*)d_in[13],(const float*)d_in[19]};
  const float* demb_W = (const float*)d_in[20]; const float* demb_b = (const float*)d_in[21];
  const float* gatW[2]  = {(const float*)d_in[22],(const float*)d_in[26]};
  const float* gatAS[2] = {(const float*)d_in[23],(const float*)d_in[27]};
  const float* gatAD[2] = {(const float*)d_in[24],(const float*)d_in[28]};
  const float* gatB[2]  = {(const float*)d_in[25],(const float*)d_in[29]};
  const float* cembW1 = (const float*)d_in[30]; const float* cembb1 = (const float*)d_in[31];
  const float* cembW2 = (const float*)d_in[32]; const float* cembb2 = (const float*)d_in[33];
  const float* regW1 = (const float*)d_in[34]; const float* regb1 = (const float*)d_in[35];
  const float* regW2 = (const float*)d_in[36]; const float* regb2 = (const float*)d_in[37];
  const float* regW3 = (const float*)d_in[38]; const float* regb3 = (const float*)d_in[39];
  const int* dei = (const int*)d_in[40];
  const int* ei0 = (const int*)d_in[42];
  const int* ei1 = (const int*)d_in[43];
  const int* cl0 = (const int*)d_in[44];
  const int* cl1 = (const int*)d_in[45];
  const int Ed  = in_sizes[40]/2;
  const int *dsrc = dei, *ddst = dei + Ed;
  const int *src0 = ei0, *dst0 = ei0 + Ec0;
  const int *src1 = ei1, *dst1 = ei1 + Ec1;
  float* out = (float*)d_out;

  // ---- workspace layout ----
  char* base = (char*)d_ws; size_t off = 0;
  auto AL = [&](size_t bytes)->char* { char* p = base + off; off = (off + bytes + 255) & ~(size_t)255; return p; };
  float* h_cat   = (float*)AL((size_t)512*384*4);
  float* xd      = (float*)AL((size_t)512*384*4);
  float* pooled1 = (float*)AL((size_t)nc1*16*4);
  float* pooled2 = (float*)AL((size_t)nc2*16*4);
  float* st_g0   = (float*)AL(256*4);
  float* st_g1   = (float*)AL(256*4);
  float* st_g2   = (float*)AL(256*4);
  float* st16_0  = (float*)AL(32*4);
  float* st16_1  = (float*)AL(32*4);
  float* bparts  = (float*)AL((size_t)512*256*4);
  unsigned short* Wt6 = (unsigned short*)AL((size_t)6*128*136*2);
  char*  S       = base + off;
  if (ws_size < off + (size_t)53*1024*1024) return;

  dim3 b256(256);

  // drug-phase scratch (S)
  float* pre0 = (float*)(S);
  float* pre1 = pre0 + (size_t)nd*128;
  float* pre2 = pre1 + (size_t)nd*128;
  unsigned short* xin_b = (unsigned short*)(pre2 + (size_t)nd*128);
  float* pre[3] = {pre0, pre1, pre2};
  float* stg[3] = {st_g0, st_g1, st_g2};

  // cell-phase scratch (S, reused after drug pool)
  size_t so = 0;
  auto SB = [&](size_t bytes)->char* { char* p = S + so; so = (so + bytes + 255) & ~(size_t)255; return p; };
  unsigned short* Abf = (unsigned short*)SB((size_t)512*6400*2);
  unsigned short* Btb = (unsigned short*)SB((size_t)1024*6400*2);
  float* parts1 = (float*)SB((size_t)8*512*1024*4);
  float* parts2 = (float*)SB((size_t)8*512*256*4);
  float* partsA = (float*)SB((size_t)4*512*384*4);
  float* partsB = (float*)SB((size_t)4*512*384*4);
  float* cembh = (float*)Abf;   // reduce dst (Abf dead post-mfma)

  // ================= DRUG BRANCH (bf16 MFMA GIN) =================
  k_w2bt6<<<dim3(68, 6), b256, 0, stream>>>(gW1[0], gW1[1], gW1[2],
                                            gW2[0], gW2[1], gW2[2], Wt6);
  for (int L = 0; L < 3; ++L) {
    if (L == 0)
      k_gin_agg_b<77,0><<<dim3(512), b256, 0, stream>>>(drug_x, nullptr, dsrc, ddst, xin_b);
    else
      k_gin_agg_b<128,1><<<dim3(512), b256, 0, stream>>>(pre[L-1], stg[L-1], dsrc, ddst, xin_b);
    k_gin_fmfma<<<dim3(320), b256, 0, stream>>>(
        xin_b, Wt6 + (size_t)L*128*136, Wt6 + (size_t)(3+L)*128*136,
        gb1[L], gb2[L], pre[L], bparts);
    k_bn_fin<<<dim3(1), dim3(512), 0, stream>>>(bparts, 320, 128, 1.f/nd, gg[L], gbe[L], stg[L]);
  }
  k_drug_pool_bn<<<dim3(512), dim3(128), 0, stream>>>(pre0, pre1, pre2, st_g0, st_g1, st_g2, xd);
  k_gemm<1,0,0,0,0,0><<<dim3(2,8,1), b256, 0, stream>>>(
      xd, 384, demb_W, 128, demb_b, h_cat, 384, 384, 0, 0, nullptr, nullptr, nullptr);

  // cembW1 -> bf16 transposed (drug scratch dead now)
  k_w2bt<<<dim3(200, 32), b256, 0, stream>>>(cembW1, Btb);

  // ================= CELL BRANCH: two fused GAT layers (BN partials in-kernel) =====
  k_gat_lds<706,512,3,8000,0,0,1024><<<dim3(512), dim3(1024), 0, stream>>>(
      cell_x, src0, dst0, Ec0/512, gatW[0], gatAS[0], gatAD[0], gatB[0], cl0,
      nullptr, pooled1, bparts);
  k_bn_fin<<<dim3(1), dim3(512), 0, stream>>>(bparts, 512, 16, 1.f/nc1, nullptr, nullptr, st16_0);

  k_gat_lds<512,400,16,8000,1,1,1024><<<dim3(512), dim3(1024), 0, stream>>>(
      pooled1, src1, dst1, Ec1, gatW[1], gatAS[1], gatAD[1], gatB[1], cl1,
      st16_0, pooled2, bparts);
  k_bn_fin<<<dim3(1), dim3(512), 0, stream>>>(bparts, 512, 16, 1.f/nc2, nullptr, nullptr, st16_1);

  // ================= cell embedding MLP =================
  k_a2bn<<<dim3(3200), b256, 0, stream>>>(pooled2, st16_1, Abf, 512*6400/4);
  k_mfma128<<<dim3(8, 4, 8), b256, 0, stream>>>(
      Abf, Btb, parts1, 1024, 6400, 800, (long)512*1024);
  k_reduce<1><<<dim3((512*1024+255)/256), b256, 0, stream>>>(
      parts1, 8, (long)512*1024, cembb1, cembh, 1024, 512, 1024);
  k_gemm<0,1,0,0,0,0><<<dim3(4,8,8), b256, 0, stream>>>(
      cembh, 1024, cembW2, 256, nullptr, parts2, 256, 128,
      (long)512*256, 0, nullptr, nullptr, nullptr);
  k_reduce<1><<<dim3((512*256+255)/256), b256, 0, stream>>>(
      parts2, 8, (long)512*256, cembb2, h_cat + 128, 384, 512, 256);

  // ================= regressor =================
  k_gemm<0,1,0,0,0,0><<<dim3(6,8,4), b256, 0, stream>>>(
      h_cat, 384, regW1, 384, nullptr, partsA, 384, 96,
      (long)512*384, 0, nullptr, nullptr, nullptr);
  k_gemm<0,1,0,4,2,0><<<dim3(6,8,4), b256, 0, stream>>>(
      partsA, 384, regW2, 384, nullptr, partsB, 384, 96,
      (long)512*384, (long)512*384, regb1, nullptr, nullptr);
  k_gemv_out<<<dim3(512), dim3(64), 0, stream>>>(
      partsB, (long)512*384, regb2, regW3, regb3, out);
}